// Round 7
// baseline (417.141 us; speedup 1.0000x reference)
//
#include <hip/hip_runtime.h>

#define NN 100000
#define NE 1600000
#define FIN 256
#define FHID 128
#define FCLS 64

// multisplit params: 512 dst-nodes per partition
#define SH1 9
#define P1 196
#define EPB 8192
#define NBLK_E ((NE + EPB - 1) / EPB)

typedef _Float16 f16;
typedef __attribute__((ext_vector_type(8))) _Float16 f16x8;
typedef __attribute__((ext_vector_type(2))) _Float16 f16x2;
typedef __attribute__((ext_vector_type(4))) float f32x4;
typedef __attribute__((ext_vector_type(2))) float f32x2;

// ---------------- pass A: per-block dst-partition histogram + outdeg ----------------
__global__ __launch_bounds__(256) void k_histA(const int* __restrict__ src, const int* __restrict__ dst,
                                               int* __restrict__ outdeg, int* __restrict__ hist2d) {
  __shared__ int lh[P1];
  int t = threadIdx.x;
  for (int i = t; i < P1; i += 256) lh[i] = 0;
  __syncthreads();
  int base = blockIdx.x * EPB;
  int cnt = NE - base; if (cnt > EPB) cnt = EPB;
  for (int i = t; i < cnt; i += 256) {
    atomicAdd(&outdeg[src[base + i]], 1);
    atomicAdd(&lh[dst[base + i] >> SH1], 1);
  }
  __syncthreads();
  for (int i = t; i < P1; i += 256) hist2d[blockIdx.x * P1 + i] = lh[i];
}

// ---------------- pass B: totals, partition bases, per-(block,partition) bases ----------------
__global__ __launch_bounds__(256) void k_pscan(const int* __restrict__ hist2d, int* __restrict__ totals,
                                               int* __restrict__ pbase, int* __restrict__ base2d,
                                               int* __restrict__ rp) {
  __shared__ int sm[256];
  int t = threadIdx.x;
  int tot = 0;
  if (t < P1) {
    for (int b = 0; b < NBLK_E; ++b) tot += hist2d[b * P1 + t];
    totals[t] = tot;
  }
  int v = (t < P1) ? tot : 0;
  int x = v;
  sm[t] = x;
  __syncthreads();
  for (int off = 1; off < 256; off <<= 1) {
    int y = (t >= off) ? sm[t - off] : 0;
    __syncthreads();
    x += y;
    sm[t] = x;
    __syncthreads();
  }
  if (t < P1) {
    int run = x - v;
    pbase[t] = run;
    for (int b = 0; b < NBLK_E; ++b) {
      base2d[b * P1 + t] = run;
      run += hist2d[b * P1 + t];
    }
  }
  if (t == 0) rp[NN] = NE;
}

// ---------------- pass C: per-block LDS counting sort -> contiguous partition runs ----------------
__global__ __launch_bounds__(256) void k_place(const int* __restrict__ src, const int* __restrict__ dst,
                                               const int* __restrict__ hist2d, const int* __restrict__ base2d,
                                               unsigned* __restrict__ staged) {
  __shared__ unsigned buf[EPB];
  __shared__ unsigned char prt[EPB];
  __shared__ int lofs[P1], lcur[P1], lbase[P1];
  __shared__ int sm[256];
  int t = threadIdx.x;
  int b = blockIdx.x;
  int v = 0;
  if (t < P1) {
    v = hist2d[b * P1 + t];
    lbase[t] = base2d[b * P1 + t];
    lcur[t] = 0;
  }
  int x = v;
  sm[t] = x;
  __syncthreads();
  for (int off = 1; off < 256; off <<= 1) {
    int y = (t >= off) ? sm[t - off] : 0;
    __syncthreads();
    x += y;
    sm[t] = x;
    __syncthreads();
  }
  if (t < P1) lofs[t] = x - v;
  __syncthreads();
  int base = b * EPB;
  int cnt = NE - base; if (cnt > EPB) cnt = EPB;
  for (int i = t; i < cnt; i += 256) {
    int s = src[base + i], d = dst[base + i];
    int p = d >> SH1;
    int pos = lofs[p] + atomicAdd(&lcur[p], 1);
    buf[pos] = ((unsigned)s << SH1) | (unsigned)(d & 511);
    prt[pos] = (unsigned char)p;
  }
  __syncthreads();
  for (int i = t; i < cnt; i += 256) {
    int p = prt[i];
    staged[lbase[p] + (i - lofs[p])] = buf[i];
  }
}

// ---------------- pass D: per-partition CSR build ----------------
__global__ __launch_bounds__(512) void k_buildp(const unsigned* __restrict__ staged, const int* __restrict__ totals,
                                                const int* __restrict__ pbase, int* __restrict__ rp,
                                                float* __restrict__ inorm, int* __restrict__ csr) {
  __shared__ int lcnt[512], lofs[512], lcur[512];
  int p = blockIdx.x, t = threadIdx.x;
  int pb = pbase[p], cnt = totals[p];
  lcnt[t] = 0;
  __syncthreads();
  const unsigned* sp = staged + pb;
  for (int i = t; i < cnt; i += 512) atomicAdd(&lcnt[sp[i] & 511], 1);
  __syncthreads();
  int v = lcnt[t];
  int x = v;
  lofs[t] = x;
  __syncthreads();
  for (int off = 1; off < 512; off <<= 1) {
    int y = (t >= off) ? lofs[t - off] : 0;
    __syncthreads();
    x += y;
    lofs[t] = x;
    __syncthreads();
  }
  int excl = x - v;
  lofs[t] = excl;
  lcur[t] = 0;
  int node = (p << SH1) + t;
  if (node < NN) {
    rp[node] = pb + excl;
    int dg = v < 1 ? 1 : v;
    inorm[node] = rsqrtf((float)dg);
  }
  __syncthreads();
  for (int i = t; i < cnt; i += 512) {
    unsigned e = sp[i];
    int d = e & 511;
    int pos = pb + lofs[d] + atomicAdd(&lcur[d], 1);
    csr[pos] = (int)(e >> SH1);
  }
}

__global__ __launch_bounds__(256) void k_onorm(const int* __restrict__ outdeg, float* __restrict__ onorm) {
  int i = blockIdx.x * 256 + threadIdx.x;
  if (i < NN) {
    int od = outdeg[i];
    if (od < 1) od = 1;
    onorm[i] = rsqrtf((float)od);
  }
}

// ---------------- weight pack: fragment-major f16 for mfma 16x16x32 ----------------
template <int K, int NW>
__global__ __launch_bounds__(256) void k_packw(const float* __restrict__ W, f16* __restrict__ Wp) {
  int idx = blockIdx.x * 256 + threadIdx.x;
  if (idx >= K * NW) return;
  constexpr int nT = NW / 16;
  int i = idx & 7;
  int l = (idx >> 3) & 63;
  int rest = idx >> 9;
  int t = rest % nT;
  int s = rest / nT;
  int k = s * 32 + (l >> 4) * 8 + i;
  int n = t * 16 + (l & 15);
  Wp[idx] = (f16)W[k * NW + n];
}

// ---------------- GEMM: [M=NN x K] @ [K x NW] via mfma_f32_16x16x32_f16 ----------------
// I/O feature-sliced in 16-wide slices: T[slice][NN][16] f16 (32 B per node-slice-row).
// MODE 0: A = f32 x (row-major), rows scaled by onorm.   (layer 1)
// MODE 1: A = f16 sliced.                                (layer 3)
// MODE 2: A = f16 sliced; epilogue relu(+bias)*onorm.    (layer 2)
template <int K, int NW, int MODE>
__global__ __launch_bounds__(256) void k_gemm(const void* __restrict__ Asrc, const f16* __restrict__ Wp,
                                              const float* __restrict__ onorm, const float* __restrict__ bias,
                                              f16* __restrict__ Out) {
  constexpr int nS = K / 32, nT = NW / 16;
  int lane = threadIdx.x & 63;
  int w = threadIdx.x >> 6;
  int bm = blockIdx.x * 64 + w * 16;
  int arow = bm + (lane & 15);
  int koff = (lane >> 4) * 8;
  bool rowok = arow < NN;

  f32x4 acc[nT];
#pragma unroll
  for (int t = 0; t < nT; ++t) acc[t] = (f32x4){0.f, 0.f, 0.f, 0.f};

  float ascale = 0.0f;
  if (MODE == 0) ascale = rowok ? onorm[arow] : 0.0f;

  for (int s = 0; s < nS; ++s) {
    f16x8 a = {};
    if (rowok) {
      if (MODE == 0) {
        const float* ap = (const float*)Asrc + (size_t)arow * K + s * 32 + koff;
        f32x4 v0 = *(const f32x4*)ap;
        f32x4 v1 = *(const f32x4*)(ap + 4);
#pragma unroll
        for (int j = 0; j < 4; ++j) {
          a[j] = (f16)(v0[j] * ascale);
          a[4 + j] = (f16)(v1[j] * ascale);
        }
      } else {
        int slice = 2 * s + (koff >> 4);
        a = *(const f16x8*)((const f16*)Asrc + ((size_t)slice * NN + arow) * 16 + (koff & 15));
      }
    }
    const f16* bp = Wp + ((size_t)(s * nT) * 64 + lane) * 8;
#pragma unroll
    for (int t = 0; t < nT; ++t) {
      f16x8 bfr = *(const f16x8*)(bp + t * 512);
      acc[t] = __builtin_amdgcn_mfma_f32_16x16x32_f16(a, bfr, acc[t], 0, 0, 0);
    }
  }

  int crow0 = bm + (lane >> 4) * 4;
  int ccol = lane & 15;
#pragma unroll
  for (int t = 0; t < nT; ++t) {
#pragma unroll
    for (int r = 0; r < 4; ++r) {
      int row = crow0 + r;
      if (row >= NN) continue;
      int col = t * 16 + ccol;
      float v = acc[t][r];
      if (MODE == 2) v = fmaxf(v + bias[col], 0.f) * onorm[row];
      Out[((size_t)t * NN + row) * 16 + ccol] = (f16)v;
    }
  }
}

// ---------------- sliced aggregation: 16B-per-lane gather, no LDS, deep pipeline ----------
// Tables [NS][NN][16] f16 (32 B rows). 2 lanes per node per slice, f16x8 loads.
// Indices read directly from global via aligned int4 (L2-hot, wave-coalesced).
// blockIdx%8 pins slices to XCDs (NS=8 -> per-XCD gather WS = 3.2 MB, L2-resident).
// MODE 0: out f16 sliced = relu(acc*inorm + bias) * onorm
// MODE 1: out f16 sliced = acc*inorm
// MODE 2: out f32 DENSE [NN][NS*16] = acc*inorm + bias   (final, NS=4 -> 64 cols)
template <int NS, int MODE>
__global__ __launch_bounds__(256) void k_aggs(const f16* __restrict__ src_arr, const int* __restrict__ rp,
                                              const int* __restrict__ csr, const float* __restrict__ inorm,
                                              const float* __restrict__ onorm, const float* __restrict__ bias,
                                              void* __restrict__ outp, float one) {
  constexpr int XPS = 8 / NS;              // XCDs per slice
  constexpr int BPS = (NN + 127) / 128;    // node-groups per slice = 782
  int bid = blockIdx.x;
  int r = bid & 7;
  int slice = r / XPS;
  int w = (bid >> 3) * XPS + (r % XPS);
  if (w >= BPS) return;
  int t = threadIdx.x;
  int node = w * 128 + (t >> 1);
  if (node >= NN) return;
  int half = t & 1;
  int beg = rp[node], end = rp[node + 1];
  const char* sbp = (const char*)src_arr + ((size_t)slice * NN * 16 + half * 8) * 2;

  float acc[8];
#pragma unroll
  for (int j = 0; j < 8; ++j) acc[j] = 0.f;

  int e = beg;
  // scalar prefix to 4-alignment (so int4 index loads are 16B-aligned)
  while (e < end && (e & 3)) {
    f16x8 v0 = *(const f16x8*)(sbp + ((size_t)(unsigned)csr[e] << 5));
#pragma unroll
    for (int j = 0; j < 8; ++j) acc[j] = fmaf((float)v0[j], one, acc[j]);
    ++e;
  }
  // main: 8 edges per iter, 2 int4 index loads + 8 f16x8 gathers in flight
  for (; e + 7 < end; e += 8) {
    int4 i0 = *(const int4*)(csr + e);
    int4 i1 = *(const int4*)(csr + e + 4);
    f16x8 v0 = *(const f16x8*)(sbp + ((size_t)(unsigned)i0.x << 5));
    f16x8 v1 = *(const f16x8*)(sbp + ((size_t)(unsigned)i0.y << 5));
    f16x8 v2 = *(const f16x8*)(sbp + ((size_t)(unsigned)i0.z << 5));
    f16x8 v3 = *(const f16x8*)(sbp + ((size_t)(unsigned)i0.w << 5));
    f16x8 v4 = *(const f16x8*)(sbp + ((size_t)(unsigned)i1.x << 5));
    f16x8 v5 = *(const f16x8*)(sbp + ((size_t)(unsigned)i1.y << 5));
    f16x8 v6 = *(const f16x8*)(sbp + ((size_t)(unsigned)i1.z << 5));
    f16x8 v7 = *(const f16x8*)(sbp + ((size_t)(unsigned)i1.w << 5));
#pragma unroll
    for (int j = 0; j < 8; ++j) {
      float s01 = fmaf((float)v0[j], one, fmaf((float)v1[j], one, 0.f));
      float s23 = fmaf((float)v2[j], one, fmaf((float)v3[j], one, 0.f));
      float s45 = fmaf((float)v4[j], one, fmaf((float)v5[j], one, 0.f));
      float s67 = fmaf((float)v6[j], one, fmaf((float)v7[j], one, 0.f));
      acc[j] += (s01 + s23) + (s45 + s67);
    }
  }
  // 4-edge step
  for (; e + 3 < end; e += 4) {
    int4 i0 = *(const int4*)(csr + e);
    f16x8 v0 = *(const f16x8*)(sbp + ((size_t)(unsigned)i0.x << 5));
    f16x8 v1 = *(const f16x8*)(sbp + ((size_t)(unsigned)i0.y << 5));
    f16x8 v2 = *(const f16x8*)(sbp + ((size_t)(unsigned)i0.z << 5));
    f16x8 v3 = *(const f16x8*)(sbp + ((size_t)(unsigned)i0.w << 5));
#pragma unroll
    for (int j = 0; j < 8; ++j) {
      float s01 = fmaf((float)v0[j], one, fmaf((float)v1[j], one, 0.f));
      float s23 = fmaf((float)v2[j], one, fmaf((float)v3[j], one, 0.f));
      acc[j] += s01 + s23;
    }
  }
  // tail
  for (; e < end; ++e) {
    f16x8 v0 = *(const f16x8*)(sbp + ((size_t)(unsigned)csr[e] << 5));
#pragma unroll
    for (int j = 0; j < 8; ++j) acc[j] = fmaf((float)v0[j], one, acc[j]);
  }

  float inn = inorm[node];
  int gfb = slice * 16 + half * 8;
  if (MODE == 0) {
    float on = onorm[node];
    f16x8 o;
#pragma unroll
    for (int j = 0; j < 8; ++j) o[j] = (f16)(fmaxf(acc[j] * inn + bias[gfb + j], 0.f) * on);
    *(f16x8*)((f16*)outp + ((size_t)slice * NN + node) * 16 + half * 8) = o;
  } else if (MODE == 1) {
    f16x8 o;
#pragma unroll
    for (int j = 0; j < 8; ++j) o[j] = (f16)(acc[j] * inn);
    *(f16x8*)((f16*)outp + ((size_t)slice * NN + node) * 16 + half * 8) = o;
  } else {
    float* op = (float*)outp + (size_t)node * (NS * 16) + gfb;
    f32x4 o0, o1;
#pragma unroll
    for (int j = 0; j < 4; ++j) {
      o0[j] = acc[j] * inn + bias[gfb + j];
      o1[j] = acc[4 + j] * inn + bias[gfb + 4 + j];
    }
    *(f32x4*)op = o0;
    *(f32x4*)(op + 4) = o1;
  }
}

extern "C" void kernel_launch(void* const* d_in, const int* in_sizes, int n_in,
                              void* d_out, int out_size, void* d_ws, size_t ws_size,
                              hipStream_t stream) {
  const float* x = (const float*)d_in[0];
  const int* src = (const int*)d_in[1];
  const int* dst = (const int*)d_in[2];
  const float* W1 = (const float*)d_in[3];
  const float* b1 = (const float*)d_in[4];
  const float* W2 = (const float*)d_in[5];
  const float* b2 = (const float*)d_in[6];
  const float* W3 = (const float*)d_in[7];
  const float* b3 = (const float*)d_in[8];

  char* base = (char*)d_ws;
  size_t off = 0;
  auto take = [&](size_t bytes) -> void* {
    void* r = base + off;
    off += (bytes + 255) & ~(size_t)255;
    return r;
  };
  int* outdeg = (int*)take((size_t)NN * 4);
  float* onorm = (float*)take((size_t)NN * 4);
  float* inorm = (float*)take((size_t)NN * 4);
  int* rp = (int*)take((size_t)(NN + 1) * 4);
  int* totals = (int*)take((size_t)P1 * 4);
  int* pbase = (int*)take((size_t)P1 * 4);
  int* hist2d = (int*)take((size_t)NBLK_E * P1 * 4);
  int* base2d = (int*)take((size_t)NBLK_E * P1 * 4);
  unsigned* staged = (unsigned*)take((size_t)NE * 4);
  int* csr = (int*)take((size_t)NE * 4);
  f16* W1p = (f16*)take((size_t)FIN * FHID * 2);
  f16* W2p = (f16*)take((size_t)FHID * FHID * 2);
  f16* W3p = (f16*)take((size_t)FHID * FCLS * 2);
  f16* B1 = (f16*)take((size_t)NN * FHID * 2);
  f16* B2 = (f16*)take((size_t)NN * FHID * 2);

  hipMemsetAsync(outdeg, 0, (size_t)NN * 4, stream);

  k_histA<<<NBLK_E, 256, 0, stream>>>(src, dst, outdeg, hist2d);
  k_pscan<<<1, 256, 0, stream>>>(hist2d, totals, pbase, base2d, rp);
  k_place<<<NBLK_E, 256, 0, stream>>>(src, dst, hist2d, base2d, staged);
  k_buildp<<<P1, 512, 0, stream>>>(staged, totals, pbase, rp, inorm, csr);
  k_onorm<<<(NN + 255) / 256, 256, 0, stream>>>(outdeg, onorm);

  k_packw<FIN, FHID><<<(FIN * FHID + 255) / 256, 256, 0, stream>>>(W1, W1p);
  k_packw<FHID, FHID><<<(FHID * FHID + 255) / 256, 256, 0, stream>>>(W2, W2p);
  k_packw<FHID, FCLS><<<(FHID * FCLS + 255) / 256, 256, 0, stream>>>(W3, W3p);

  const int gemm_grid = (NN + 63) / 64;
  const int bps = (NN + 127) / 128;            // 782
  const int agg8_grid = bps * 8;               // 6256 (XPS=1)
  const int agg4_grid = ((bps + 1) / 2) * 8;   // 3128 (XPS=2)
  // layer 1: t1 = (x*onorm) @ W1  -> sliced B1 (8 slices)
  k_gemm<FIN, FHID, 0><<<gemm_grid, 256, 0, stream>>>(x, W1p, onorm, nullptr, B1);
  // g1 = relu(agg(t1)*inorm + b1) * onorm  -> sliced B2
  k_aggs<8, 0><<<agg8_grid, 256, 0, stream>>>(B1, rp, csr, inorm, onorm, b1, B2, 1.0f);
  // agg2 = agg(g1)*inorm  -> sliced B1
  k_aggs<8, 1><<<agg8_grid, 256, 0, stream>>>(B2, rp, csr, inorm, nullptr, nullptr, B1, 1.0f);
  // g2 = relu(agg2 @ W2 + b2) * onorm  -> sliced B2
  k_gemm<FHID, FHID, 2><<<gemm_grid, 256, 0, stream>>>(B1, W2p, onorm, b2, B2);
  // t3 = g2 @ W3  -> sliced B1 (4 slices used)
  k_gemm<FHID, FCLS, 1><<<gemm_grid, 256, 0, stream>>>(B2, W3p, nullptr, nullptr, B1);
  // out = agg(t3)*inorm + b3  -> dense f32 d_out
  k_aggs<4, 2><<<agg4_grid, 256, 0, stream>>>(B1, rp, csr, inorm, nullptr, b3, d_out, 1.0f);
}

// Round 8
// 416.739 us; speedup vs baseline: 1.0010x; 1.0010x over previous
//
#include <hip/hip_runtime.h>

#define NN 100000
#define NE 1600000
#define FIN 256
#define FHID 128
#define FCLS 64

// multisplit params: 512 dst-nodes per partition
#define SH1 9
#define P1 196
#define EPB 8192
#define NBLK_E ((NE + EPB - 1) / EPB)

typedef _Float16 f16;
typedef __attribute__((ext_vector_type(8))) _Float16 f16x8;
typedef __attribute__((ext_vector_type(2))) _Float16 f16x2;
typedef __attribute__((ext_vector_type(4))) float f32x4;
typedef __attribute__((ext_vector_type(2))) float f32x2;

// ---------------- pass A: per-block dst-partition histogram + outdeg ----------------
__global__ __launch_bounds__(256) void k_histA(const int* __restrict__ src, const int* __restrict__ dst,
                                               int* __restrict__ outdeg, int* __restrict__ hist2d) {
  __shared__ int lh[P1];
  int t = threadIdx.x;
  for (int i = t; i < P1; i += 256) lh[i] = 0;
  __syncthreads();
  int base = blockIdx.x * EPB;
  int cnt = NE - base; if (cnt > EPB) cnt = EPB;
  for (int i = t; i < cnt; i += 256) {
    atomicAdd(&outdeg[src[base + i]], 1);
    atomicAdd(&lh[dst[base + i] >> SH1], 1);
  }
  __syncthreads();
  for (int i = t; i < P1; i += 256) hist2d[blockIdx.x * P1 + i] = lh[i];
}

// ---------------- pass B: totals, partition bases, per-(block,partition) bases ----------------
__global__ __launch_bounds__(256) void k_pscan(const int* __restrict__ hist2d, int* __restrict__ totals,
                                               int* __restrict__ pbase, int* __restrict__ base2d,
                                               int* __restrict__ rp) {
  __shared__ int sm[256];
  int t = threadIdx.x;
  int tot = 0;
  if (t < P1) {
    for (int b = 0; b < NBLK_E; ++b) tot += hist2d[b * P1 + t];
    totals[t] = tot;
  }
  int v = (t < P1) ? tot : 0;
  int x = v;
  sm[t] = x;
  __syncthreads();
  for (int off = 1; off < 256; off <<= 1) {
    int y = (t >= off) ? sm[t - off] : 0;
    __syncthreads();
    x += y;
    sm[t] = x;
    __syncthreads();
  }
  if (t < P1) {
    int run = x - v;
    pbase[t] = run;
    for (int b = 0; b < NBLK_E; ++b) {
      base2d[b * P1 + t] = run;
      run += hist2d[b * P1 + t];
    }
  }
  if (t == 0) rp[NN] = NE;
}

// ---------------- pass C: per-block LDS counting sort -> contiguous partition runs ----------------
__global__ __launch_bounds__(256) void k_place(const int* __restrict__ src, const int* __restrict__ dst,
                                               const int* __restrict__ hist2d, const int* __restrict__ base2d,
                                               unsigned* __restrict__ staged) {
  __shared__ unsigned buf[EPB];
  __shared__ unsigned char prt[EPB];
  __shared__ int lofs[P1], lcur[P1], lbase[P1];
  __shared__ int sm[256];
  int t = threadIdx.x;
  int b = blockIdx.x;
  int v = 0;
  if (t < P1) {
    v = hist2d[b * P1 + t];
    lbase[t] = base2d[b * P1 + t];
    lcur[t] = 0;
  }
  int x = v;
  sm[t] = x;
  __syncthreads();
  for (int off = 1; off < 256; off <<= 1) {
    int y = (t >= off) ? sm[t - off] : 0;
    __syncthreads();
    x += y;
    sm[t] = x;
    __syncthreads();
  }
  if (t < P1) lofs[t] = x - v;
  __syncthreads();
  int base = b * EPB;
  int cnt = NE - base; if (cnt > EPB) cnt = EPB;
  for (int i = t; i < cnt; i += 256) {
    int s = src[base + i], d = dst[base + i];
    int p = d >> SH1;
    int pos = lofs[p] + atomicAdd(&lcur[p], 1);
    buf[pos] = ((unsigned)s << SH1) | (unsigned)(d & 511);
    prt[pos] = (unsigned char)p;
  }
  __syncthreads();
  for (int i = t; i < cnt; i += 256) {
    int p = prt[i];
    staged[lbase[p] + (i - lofs[p])] = buf[i];
  }
}

// ---------------- pass D: per-partition CSR build ----------------
__global__ __launch_bounds__(512) void k_buildp(const unsigned* __restrict__ staged, const int* __restrict__ totals,
                                                const int* __restrict__ pbase, int* __restrict__ rp,
                                                float* __restrict__ inorm, int* __restrict__ csr) {
  __shared__ int lcnt[512], lofs[512], lcur[512];
  int p = blockIdx.x, t = threadIdx.x;
  int pb = pbase[p], cnt = totals[p];
  lcnt[t] = 0;
  __syncthreads();
  const unsigned* sp = staged + pb;
  for (int i = t; i < cnt; i += 512) atomicAdd(&lcnt[sp[i] & 511], 1);
  __syncthreads();
  int v = lcnt[t];
  int x = v;
  lofs[t] = x;
  __syncthreads();
  for (int off = 1; off < 512; off <<= 1) {
    int y = (t >= off) ? lofs[t - off] : 0;
    __syncthreads();
    x += y;
    lofs[t] = x;
    __syncthreads();
  }
  int excl = x - v;
  lofs[t] = excl;
  lcur[t] = 0;
  int node = (p << SH1) + t;
  if (node < NN) {
    rp[node] = pb + excl;
    int dg = v < 1 ? 1 : v;
    inorm[node] = rsqrtf((float)dg);
  }
  __syncthreads();
  for (int i = t; i < cnt; i += 512) {
    unsigned e = sp[i];
    int d = e & 511;
    int pos = pb + lofs[d] + atomicAdd(&lcur[d], 1);
    csr[pos] = (int)(e >> SH1);
  }
}

__global__ __launch_bounds__(256) void k_onorm(const int* __restrict__ outdeg, float* __restrict__ onorm) {
  int i = blockIdx.x * 256 + threadIdx.x;
  if (i < NN) {
    int od = outdeg[i];
    if (od < 1) od = 1;
    onorm[i] = rsqrtf((float)od);
  }
}

// ---------------- weight pack: fragment-major f16 for mfma 16x16x32 ----------------
template <int K, int NW>
__global__ __launch_bounds__(256) void k_packw(const float* __restrict__ W, f16* __restrict__ Wp) {
  int idx = blockIdx.x * 256 + threadIdx.x;
  if (idx >= K * NW) return;
  constexpr int nT = NW / 16;
  int i = idx & 7;
  int l = (idx >> 3) & 63;
  int rest = idx >> 9;
  int t = rest % nT;
  int s = rest / nT;
  int k = s * 32 + (l >> 4) * 8 + i;
  int n = t * 16 + (l & 15);
  Wp[idx] = (f16)W[k * NW + n];
}

// ---------------- GEMM: [M=NN x K] @ [K x NW] via mfma_f32_16x16x32_f16 ----------------
// I/O feature-sliced in 16-wide slices: T[slice][NN][16] f16 (32 B per node-slice-row).
// MODE 0: A = f32 x (row-major), rows scaled by onorm.   (layer 1)
// MODE 1: A = f16 sliced.                                (layer 3)
// MODE 2: A = f16 sliced; epilogue relu(+bias)*onorm.    (layer 2)
template <int K, int NW, int MODE>
__global__ __launch_bounds__(256) void k_gemm(const void* __restrict__ Asrc, const f16* __restrict__ Wp,
                                              const float* __restrict__ onorm, const float* __restrict__ bias,
                                              f16* __restrict__ Out) {
  constexpr int nS = K / 32, nT = NW / 16;
  int lane = threadIdx.x & 63;
  int w = threadIdx.x >> 6;
  int bm = blockIdx.x * 64 + w * 16;
  int arow = bm + (lane & 15);
  int koff = (lane >> 4) * 8;
  bool rowok = arow < NN;

  f32x4 acc[nT];
#pragma unroll
  for (int t = 0; t < nT; ++t) acc[t] = (f32x4){0.f, 0.f, 0.f, 0.f};

  float ascale = 0.0f;
  if (MODE == 0) ascale = rowok ? onorm[arow] : 0.0f;

  for (int s = 0; s < nS; ++s) {
    f16x8 a = {};
    if (rowok) {
      if (MODE == 0) {
        const float* ap = (const float*)Asrc + (size_t)arow * K + s * 32 + koff;
        f32x4 v0 = *(const f32x4*)ap;
        f32x4 v1 = *(const f32x4*)(ap + 4);
#pragma unroll
        for (int j = 0; j < 4; ++j) {
          a[j] = (f16)(v0[j] * ascale);
          a[4 + j] = (f16)(v1[j] * ascale);
        }
      } else {
        int slice = 2 * s + (koff >> 4);
        a = *(const f16x8*)((const f16*)Asrc + ((size_t)slice * NN + arow) * 16 + (koff & 15));
      }
    }
    const f16* bp = Wp + ((size_t)(s * nT) * 64 + lane) * 8;
#pragma unroll
    for (int t = 0; t < nT; ++t) {
      f16x8 bfr = *(const f16x8*)(bp + t * 512);
      acc[t] = __builtin_amdgcn_mfma_f32_16x16x32_f16(a, bfr, acc[t], 0, 0, 0);
    }
  }

  int crow0 = bm + (lane >> 4) * 4;
  int ccol = lane & 15;
#pragma unroll
  for (int t = 0; t < nT; ++t) {
#pragma unroll
    for (int r = 0; r < 4; ++r) {
      int row = crow0 + r;
      if (row >= NN) continue;
      int col = t * 16 + ccol;
      float v = acc[t][r];
      if (MODE == 2) v = fmaxf(v + bias[col], 0.f) * onorm[row];
      Out[((size_t)t * NN + row) * 16 + ccol] = (f16)v;
    }
  }
}

// ---------------- sliced aggregation: 16B-per-lane gather, no LDS, deep pipeline ----------
// Tables [NS][NN][16] f16 (32 B rows). 2 lanes per node per slice, f16x8 loads.
// Indices read directly from global via aligned int4 (L2-hot, wave-coalesced).
// blockIdx%8 pins slices to XCDs (NS=8 -> per-XCD gather WS = 3.2 MB, L2-resident).
// MODE 0: out f16 sliced = relu(acc*inorm + bias) * onorm
// MODE 1: out f16 sliced = acc*inorm
// MODE 2: out f32 DENSE [NN][NS*16] = acc*inorm + bias   (final, NS=4 -> 64 cols)
template <int NS, int MODE>
__global__ __launch_bounds__(256) void k_aggs(const f16* __restrict__ src_arr, const int* __restrict__ rp,
                                              const int* __restrict__ csr, const float* __restrict__ inorm,
                                              const float* __restrict__ onorm, const float* __restrict__ bias,
                                              void* __restrict__ outp, float one) {
  constexpr int XPS = 8 / NS;              // XCDs per slice
  constexpr int BPS = (NN + 127) / 128;    // node-groups per slice = 782
  int bid = blockIdx.x;
  int r = bid & 7;
  int slice = r / XPS;
  int w = (bid >> 3) * XPS + (r % XPS);
  if (w >= BPS) return;
  int t = threadIdx.x;
  int node = w * 128 + (t >> 1);
  if (node >= NN) return;
  int half = t & 1;
  int beg = rp[node], end = rp[node + 1];
  const char* sbp = (const char*)src_arr + ((size_t)slice * NN * 16 + half * 8) * 2;

  float acc[8];
#pragma unroll
  for (int j = 0; j < 8; ++j) acc[j] = 0.f;

  int e = beg;
  // scalar prefix to 4-alignment (so int4 index loads are 16B-aligned)
  while (e < end && (e & 3)) {
    f16x8 v0 = *(const f16x8*)(sbp + ((size_t)(unsigned)csr[e] << 5));
#pragma unroll
    for (int j = 0; j < 8; ++j) acc[j] = fmaf((float)v0[j], one, acc[j]);
    ++e;
  }
  // main: 8 edges per iter, 2 int4 index loads + 8 f16x8 gathers in flight
  for (; e + 7 < end; e += 8) {
    int4 i0 = *(const int4*)(csr + e);
    int4 i1 = *(const int4*)(csr + e + 4);
    f16x8 v0 = *(const f16x8*)(sbp + ((size_t)(unsigned)i0.x << 5));
    f16x8 v1 = *(const f16x8*)(sbp + ((size_t)(unsigned)i0.y << 5));
    f16x8 v2 = *(const f16x8*)(sbp + ((size_t)(unsigned)i0.z << 5));
    f16x8 v3 = *(const f16x8*)(sbp + ((size_t)(unsigned)i0.w << 5));
    f16x8 v4 = *(const f16x8*)(sbp + ((size_t)(unsigned)i1.x << 5));
    f16x8 v5 = *(const f16x8*)(sbp + ((size_t)(unsigned)i1.y << 5));
    f16x8 v6 = *(const f16x8*)(sbp + ((size_t)(unsigned)i1.z << 5));
    f16x8 v7 = *(const f16x8*)(sbp + ((size_t)(unsigned)i1.w << 5));
#pragma unroll
    for (int j = 0; j < 8; ++j) {
      float s01 = fmaf((float)v0[j], one, fmaf((float)v1[j], one, 0.f));
      float s23 = fmaf((float)v2[j], one, fmaf((float)v3[j], one, 0.f));
      float s45 = fmaf((float)v4[j], one, fmaf((float)v5[j], one, 0.f));
      float s67 = fmaf((float)v6[j], one, fmaf((float)v7[j], one, 0.f));
      acc[j] += (s01 + s23) + (s45 + s67);
    }
  }
  // 4-edge step
  for (; e + 3 < end; e += 4) {
    int4 i0 = *(const int4*)(csr + e);
    f16x8 v0 = *(const f16x8*)(sbp + ((size_t)(unsigned)i0.x << 5));
    f16x8 v1 = *(const f16x8*)(sbp + ((size_t)(unsigned)i0.y << 5));
    f16x8 v2 = *(const f16x8*)(sbp + ((size_t)(unsigned)i0.z << 5));
    f16x8 v3 = *(const f16x8*)(sbp + ((size_t)(unsigned)i0.w << 5));
#pragma unroll
    for (int j = 0; j < 8; ++j) {
      float s01 = fmaf((float)v0[j], one, fmaf((float)v1[j], one, 0.f));
      float s23 = fmaf((float)v2[j], one, fmaf((float)v3[j], one, 0.f));
      acc[j] += s01 + s23;
    }
  }
  // tail
  for (; e < end; ++e) {
    f16x8 v0 = *(const f16x8*)(sbp + ((size_t)(unsigned)csr[e] << 5));
#pragma unroll
    for (int j = 0; j < 8; ++j) acc[j] = fmaf((float)v0[j], one, acc[j]);
  }

  float inn = inorm[node];
  int gfb = slice * 16 + half * 8;
  if (MODE == 0) {
    float on = onorm[node];
    f16x8 o;
#pragma unroll
    for (int j = 0; j < 8; ++j) o[j] = (f16)(fmaxf(acc[j] * inn + bias[gfb + j], 0.f) * on);
    *(f16x8*)((f16*)outp + ((size_t)slice * NN + node) * 16 + half * 8) = o;
  } else if (MODE == 1) {
    f16x8 o;
#pragma unroll
    for (int j = 0; j < 8; ++j) o[j] = (f16)(acc[j] * inn);
    *(f16x8*)((f16*)outp + ((size_t)slice * NN + node) * 16 + half * 8) = o;
  } else {
    float* op = (float*)outp + (size_t)node * (NS * 16) + gfb;
    f32x4 o0, o1;
#pragma unroll
    for (int j = 0; j < 4; ++j) {
      o0[j] = acc[j] * inn + bias[gfb + j];
      o1[j] = acc[4 + j] * inn + bias[gfb + 4 + j];
    }
    *(f32x4*)op = o0;
    *(f32x4*)(op + 4) = o1;
  }
}

extern "C" void kernel_launch(void* const* d_in, const int* in_sizes, int n_in,
                              void* d_out, int out_size, void* d_ws, size_t ws_size,
                              hipStream_t stream) {
  const float* x = (const float*)d_in[0];
  const int* src = (const int*)d_in[1];
  const int* dst = (const int*)d_in[2];
  const float* W1 = (const float*)d_in[3];
  const float* b1 = (const float*)d_in[4];
  const float* W2 = (const float*)d_in[5];
  const float* b2 = (const float*)d_in[6];
  const float* W3 = (const float*)d_in[7];
  const float* b3 = (const float*)d_in[8];

  char* base = (char*)d_ws;
  size_t off = 0;
  auto take = [&](size_t bytes) -> void* {
    void* r = base + off;
    off += (bytes + 255) & ~(size_t)255;
    return r;
  };
  int* outdeg = (int*)take((size_t)NN * 4);
  float* onorm = (float*)take((size_t)NN * 4);
  float* inorm = (float*)take((size_t)NN * 4);
  int* rp = (int*)take((size_t)(NN + 1) * 4);
  int* totals = (int*)take((size_t)P1 * 4);
  int* pbase = (int*)take((size_t)P1 * 4);
  int* hist2d = (int*)take((size_t)NBLK_E * P1 * 4);
  int* base2d = (int*)take((size_t)NBLK_E * P1 * 4);
  unsigned* staged = (unsigned*)take((size_t)NE * 4);
  int* csr = (int*)take((size_t)NE * 4);
  f16* W1p = (f16*)take((size_t)FIN * FHID * 2);
  f16* W2p = (f16*)take((size_t)FHID * FHID * 2);
  f16* W3p = (f16*)take((size_t)FHID * FCLS * 2);
  f16* B1 = (f16*)take((size_t)NN * FHID * 2);
  f16* B2 = (f16*)take((size_t)NN * FHID * 2);

  hipMemsetAsync(outdeg, 0, (size_t)NN * 4, stream);

  k_histA<<<NBLK_E, 256, 0, stream>>>(src, dst, outdeg, hist2d);
  k_pscan<<<1, 256, 0, stream>>>(hist2d, totals, pbase, base2d, rp);
  k_place<<<NBLK_E, 256, 0, stream>>>(src, dst, hist2d, base2d, staged);
  k_buildp<<<P1, 512, 0, stream>>>(staged, totals, pbase, rp, inorm, csr);
  k_onorm<<<(NN + 255) / 256, 256, 0, stream>>>(outdeg, onorm);

  k_packw<FIN, FHID><<<(FIN * FHID + 255) / 256, 256, 0, stream>>>(W1, W1p);
  k_packw<FHID, FHID><<<(FHID * FHID + 255) / 256, 256, 0, stream>>>(W2, W2p);
  k_packw<FHID, FCLS><<<(FHID * FCLS + 255) / 256, 256, 0, stream>>>(W3, W3p);

  const int gemm_grid = (NN + 63) / 64;
  const int bps = (NN + 127) / 128;            // 782
  const int agg8_grid = bps * 8;               // 6256 (XPS=1)
  const int agg4_grid = ((bps + 1) / 2) * 8;   // 3128 (XPS=2)
  // layer 1: t1 = (x*onorm) @ W1  -> sliced B1 (8 slices)
  k_gemm<FIN, FHID, 0><<<gemm_grid, 256, 0, stream>>>(x, W1p, onorm, nullptr, B1);
  // g1 = relu(agg(t1)*inorm + b1) * onorm  -> sliced B2
  k_aggs<8, 0><<<agg8_grid, 256, 0, stream>>>(B1, rp, csr, inorm, onorm, b1, B2, 1.0f);
  // agg2 = agg(g1)*inorm  -> sliced B1
  k_aggs<8, 1><<<agg8_grid, 256, 0, stream>>>(B2, rp, csr, inorm, nullptr, nullptr, B1, 1.0f);
  // g2 = relu(agg2 @ W2 + b2) * onorm  -> sliced B2
  k_gemm<FHID, FHID, 2><<<gemm_grid, 256, 0, stream>>>(B1, W2p, onorm, b2, B2);
  // t3 = g2 @ W3  -> sliced B1 (4 slices used)
  k_gemm<FHID, FCLS, 1><<<gemm_grid, 256, 0, stream>>>(B2, W3p, nullptr, nullptr, B1);
  // out = agg(t3)*inorm + b3  -> dense f32 d_out
  k_aggs<4, 2><<<agg4_grid, 256, 0, stream>>>(B1, rp, csr, inorm, nullptr, b3, d_out, 1.0f);
}

// Round 9
// 403.580 us; speedup vs baseline: 1.0336x; 1.0326x over previous
//
#include <hip/hip_runtime.h>

#define NN 100000
#define NE 1600000
#define FIN 256
#define FHID 128
#define FCLS 64

// multisplit params: 512 dst-nodes per partition
#define SH1 9
#define P1 196
#define EPB 8192
#define NBLK_E ((NE + EPB - 1) / EPB)

#define DBINS 64            // degree bins (Poisson(16): P(deg>=63) ~ 0)

typedef _Float16 f16;
typedef __attribute__((ext_vector_type(8))) _Float16 f16x8;
typedef __attribute__((ext_vector_type(2))) _Float16 f16x2;
typedef __attribute__((ext_vector_type(4))) float f32x4;
typedef __attribute__((ext_vector_type(2))) float f32x2;

// ---------------- pass A: per-block dst-partition histogram + outdeg ----------------
__global__ __launch_bounds__(256) void k_histA(const int* __restrict__ src, const int* __restrict__ dst,
                                               int* __restrict__ outdeg, int* __restrict__ hist2d) {
  __shared__ int lh[P1];
  int t = threadIdx.x;
  for (int i = t; i < P1; i += 256) lh[i] = 0;
  __syncthreads();
  int base = blockIdx.x * EPB;
  int cnt = NE - base; if (cnt > EPB) cnt = EPB;
  for (int i = t; i < cnt; i += 256) {
    atomicAdd(&outdeg[src[base + i]], 1);
    atomicAdd(&lh[dst[base + i] >> SH1], 1);
  }
  __syncthreads();
  for (int i = t; i < P1; i += 256) hist2d[blockIdx.x * P1 + i] = lh[i];
}

// ---------------- pass B: totals, partition bases, per-(block,partition) bases ----------------
__global__ __launch_bounds__(256) void k_pscan(const int* __restrict__ hist2d, int* __restrict__ totals,
                                               int* __restrict__ pbase, int* __restrict__ base2d,
                                               int* __restrict__ rp) {
  __shared__ int sm[256];
  int t = threadIdx.x;
  int tot = 0;
  if (t < P1) {
    for (int b = 0; b < NBLK_E; ++b) tot += hist2d[b * P1 + t];
    totals[t] = tot;
  }
  int v = (t < P1) ? tot : 0;
  int x = v;
  sm[t] = x;
  __syncthreads();
  for (int off = 1; off < 256; off <<= 1) {
    int y = (t >= off) ? sm[t - off] : 0;
    __syncthreads();
    x += y;
    sm[t] = x;
    __syncthreads();
  }
  if (t < P1) {
    int run = x - v;
    pbase[t] = run;
    for (int b = 0; b < NBLK_E; ++b) {
      base2d[b * P1 + t] = run;
      run += hist2d[b * P1 + t];
    }
  }
  if (t == 0) rp[NN] = NE;
}

// ---------------- pass C: per-block LDS counting sort -> contiguous partition runs ----------------
__global__ __launch_bounds__(256) void k_place(const int* __restrict__ src, const int* __restrict__ dst,
                                               const int* __restrict__ hist2d, const int* __restrict__ base2d,
                                               unsigned* __restrict__ staged) {
  __shared__ unsigned buf[EPB];
  __shared__ unsigned char prt[EPB];
  __shared__ int lofs[P1], lcur[P1], lbase[P1];
  __shared__ int sm[256];
  int t = threadIdx.x;
  int b = blockIdx.x;
  int v = 0;
  if (t < P1) {
    v = hist2d[b * P1 + t];
    lbase[t] = base2d[b * P1 + t];
    lcur[t] = 0;
  }
  int x = v;
  sm[t] = x;
  __syncthreads();
  for (int off = 1; off < 256; off <<= 1) {
    int y = (t >= off) ? sm[t - off] : 0;
    __syncthreads();
    x += y;
    sm[t] = x;
    __syncthreads();
  }
  if (t < P1) lofs[t] = x - v;
  __syncthreads();
  int base = b * EPB;
  int cnt = NE - base; if (cnt > EPB) cnt = EPB;
  for (int i = t; i < cnt; i += 256) {
    int s = src[base + i], d = dst[base + i];
    int p = d >> SH1;
    int pos = lofs[p] + atomicAdd(&lcur[p], 1);
    buf[pos] = ((unsigned)s << SH1) | (unsigned)(d & 511);
    prt[pos] = (unsigned char)p;
  }
  __syncthreads();
  for (int i = t; i < cnt; i += 256) {
    int p = prt[i];
    staged[lbase[p] + (i - lofs[p])] = buf[i];
  }
}

// ---------------- pass D: per-partition CSR build (+ degree + degree histogram) ------
__global__ __launch_bounds__(512) void k_buildp(const unsigned* __restrict__ staged, const int* __restrict__ totals,
                                                const int* __restrict__ pbase, int* __restrict__ rp,
                                                float* __restrict__ inorm, int* __restrict__ csr,
                                                int* __restrict__ deg, int* __restrict__ dhist2d) {
  __shared__ int lcnt[512], lofs[512], lcur[512];
  __shared__ int dh[DBINS];
  int p = blockIdx.x, t = threadIdx.x;
  int pb = pbase[p], cnt = totals[p];
  lcnt[t] = 0;
  if (t < DBINS) dh[t] = 0;
  __syncthreads();
  const unsigned* sp = staged + pb;
  for (int i = t; i < cnt; i += 512) atomicAdd(&lcnt[sp[i] & 511], 1);
  __syncthreads();
  int v = lcnt[t];
  int x = v;
  lofs[t] = x;
  __syncthreads();
  for (int off = 1; off < 512; off <<= 1) {
    int y = (t >= off) ? lofs[t - off] : 0;
    __syncthreads();
    x += y;
    lofs[t] = x;
    __syncthreads();
  }
  int excl = x - v;
  lofs[t] = excl;
  lcur[t] = 0;
  int node = (p << SH1) + t;
  if (node < NN) {
    rp[node] = pb + excl;
    deg[node] = v;
    int bin = v > (DBINS - 1) ? (DBINS - 1) : v;
    atomicAdd(&dh[bin], 1);
    int dg = v < 1 ? 1 : v;
    inorm[node] = rsqrtf((float)dg);
  }
  __syncthreads();
  if (t < DBINS) dhist2d[p * DBINS + t] = dh[t];
  for (int i = t; i < cnt; i += 512) {
    unsigned e = sp[i];
    int d = e & 511;
    int pos = pb + lofs[d] + atomicAdd(&lcur[d], 1);
    csr[pos] = (int)(e >> SH1);
  }
}

__global__ __launch_bounds__(256) void k_onorm(const int* __restrict__ outdeg, float* __restrict__ onorm) {
  int i = blockIdx.x * 256 + threadIdx.x;
  if (i < NN) {
    int od = outdeg[i];
    if (od < 1) od = 1;
    onorm[i] = rsqrtf((float)od);
  }
}

// ---------------- degree-sort pass 1: bin totals, node/edge bases ----------------
__global__ __launch_bounds__(256) void k_dscan(const int* __restrict__ dhist2d, int* __restrict__ nbase_g,
                                               int* __restrict__ ebase_g, int* __restrict__ dbase2d,
                                               int* __restrict__ rp_p) {
  __shared__ int cnt[DBINS];
  int t = threadIdx.x;
  if (t < DBINS) {
    int tot = 0;
    for (int b = 0; b < P1; ++b) tot += dhist2d[b * DBINS + t];
    cnt[t] = tot;
  }
  __syncthreads();
  if (t == 0) {
    int nrun = 0, erun = 0;
    for (int i = 0; i < DBINS; ++i) {
      nbase_g[i] = nrun;
      ebase_g[i] = erun;
      nrun += cnt[i];
      erun += cnt[i] * i;
    }
    rp_p[NN] = NE;
  }
  __syncthreads();
  if (t < DBINS) {
    int run = nbase_g[t];
    for (int b = 0; b < P1; ++b) {
      dbase2d[b * DBINS + t] = run;
      run += dhist2d[b * DBINS + t];
    }
  }
}

// ---------------- degree-sort pass 2: place nodes, emit perm + rp_p ----------------
__global__ __launch_bounds__(512) void k_dplace(const int* __restrict__ deg, const int* __restrict__ dbase2d,
                                                const int* __restrict__ nbase_g, const int* __restrict__ ebase_g,
                                                int* __restrict__ perm, int* __restrict__ rp_p) {
  __shared__ int lcur[DBINS];
  int p = blockIdx.x, t = threadIdx.x;
  if (t < DBINS) lcur[t] = 0;
  __syncthreads();
  int node = p * 512 + t;
  if (node < NN) {
    int v = deg[node];
    int bin = v > (DBINS - 1) ? (DBINS - 1) : v;
    int rl = atomicAdd(&lcur[bin], 1);
    int npos = dbase2d[p * DBINS + bin] + rl;
    perm[npos] = node;
    int grank = npos - nbase_g[bin];
    rp_p[npos] = ebase_g[bin] + grank * v;
  }
}

// ---------------- degree-sort pass 3: remap CSR into perm order + permuted norms ------
__global__ __launch_bounds__(256) void k_remap(const int* __restrict__ perm, const int* __restrict__ rp,
                                               const int* __restrict__ rp_p, const int* __restrict__ csr,
                                               const float* __restrict__ inorm, const float* __restrict__ onorm,
                                               int* __restrict__ csr_p, float* __restrict__ inorm_p,
                                               float* __restrict__ onorm_p) {
  int t = threadIdx.x;
  int i = blockIdx.x * 128 + (t >> 1);
  if (i >= NN) return;
  int orig = perm[i];
  int b0 = rp[orig];
  int len = rp[orig + 1] - b0;
  int o = rp_p[i];
  for (int k = t & 1; k < len; k += 2) csr_p[o + k] = csr[b0 + k];
  if ((t & 1) == 0) {
    inorm_p[i] = inorm[orig];
    onorm_p[i] = onorm[orig];
  }
}

// ---------------- weight pack: fragment-major f16 for mfma 16x16x32 ----------------
template <int K, int NW>
__global__ __launch_bounds__(256) void k_packw(const float* __restrict__ W, f16* __restrict__ Wp) {
  int idx = blockIdx.x * 256 + threadIdx.x;
  if (idx >= K * NW) return;
  constexpr int nT = NW / 16;
  int i = idx & 7;
  int l = (idx >> 3) & 63;
  int rest = idx >> 9;
  int t = rest % nT;
  int s = rest / nT;
  int k = s * 32 + (l >> 4) * 8 + i;
  int n = t * 16 + (l & 15);
  Wp[idx] = (f16)W[k * NW + n];
}

// ---------------- GEMM: [M=NN x K] @ [K x NW] via mfma_f32_16x16x32_f16 ----------------
// I/O feature-sliced in 16-wide slices: T[slice][NN][16] f16 (32 B per node-slice-row).
template <int K, int NW, int MODE>
__global__ __launch_bounds__(256) void k_gemm(const void* __restrict__ Asrc, const f16* __restrict__ Wp,
                                              const float* __restrict__ onorm, const float* __restrict__ bias,
                                              f16* __restrict__ Out) {
  constexpr int nS = K / 32, nT = NW / 16;
  int lane = threadIdx.x & 63;
  int w = threadIdx.x >> 6;
  int bm = blockIdx.x * 64 + w * 16;
  int arow = bm + (lane & 15);
  int koff = (lane >> 4) * 8;
  bool rowok = arow < NN;

  f32x4 acc[nT];
#pragma unroll
  for (int t = 0; t < nT; ++t) acc[t] = (f32x4){0.f, 0.f, 0.f, 0.f};

  float ascale = 0.0f;
  if (MODE == 0) ascale = rowok ? onorm[arow] : 0.0f;

  for (int s = 0; s < nS; ++s) {
    f16x8 a = {};
    if (rowok) {
      if (MODE == 0) {
        const float* ap = (const float*)Asrc + (size_t)arow * K + s * 32 + koff;
        f32x4 v0 = *(const f32x4*)ap;
        f32x4 v1 = *(const f32x4*)(ap + 4);
#pragma unroll
        for (int j = 0; j < 4; ++j) {
          a[j] = (f16)(v0[j] * ascale);
          a[4 + j] = (f16)(v1[j] * ascale);
        }
      } else {
        int slice = 2 * s + (koff >> 4);
        a = *(const f16x8*)((const f16*)Asrc + ((size_t)slice * NN + arow) * 16 + (koff & 15));
      }
    }
    const f16* bp = Wp + ((size_t)(s * nT) * 64 + lane) * 8;
#pragma unroll
    for (int t = 0; t < nT; ++t) {
      f16x8 bfr = *(const f16x8*)(bp + t * 512);
      acc[t] = __builtin_amdgcn_mfma_f32_16x16x32_f16(a, bfr, acc[t], 0, 0, 0);
    }
  }

  int crow0 = bm + (lane >> 4) * 4;
  int ccol = lane & 15;
#pragma unroll
  for (int t = 0; t < nT; ++t) {
#pragma unroll
    for (int r = 0; r < 4; ++r) {
      int row = crow0 + r;
      if (row >= NN) continue;
      int col = t * 16 + ccol;
      float v = acc[t][r];
      if (MODE == 2) v = fmaxf(v + bias[col], 0.f) * onorm[row];
      Out[((size_t)t * NN + row) * 16 + ccol] = (f16)v;
    }
  }
}

// ---------------- sliced aggregation over degree-sorted permuted CSR ----------------
// Tables [NS][NN][16] f16 (32 B rows, indexed by ORIGINAL src id). 2 lanes/node, f16x8.
// Nodes processed in perm order (degree-sorted -> uniform wave loop bounds).
// Block = 128 perm-nodes; contiguous csr_p span staged to LDS with +i>>4 swizzle
// (uniform stride-16 index patterns would otherwise be 16-way bank conflicts).
// blockIdx%8 pins slices to XCDs (per-XCD gather WS = 3.2 MB, L2-resident).
#define LCSR_CAP 4608               // 128 nodes * deg<=36; P(deg>36)~1e-6
#define LCSR_STORE (LCSR_CAP + (LCSR_CAP >> 4))
template <int NS, int MODE>
__global__ __launch_bounds__(256) void k_aggs(const f16* __restrict__ src_arr, const int* __restrict__ rp_p,
                                              const int* __restrict__ csr_p, const int* __restrict__ perm,
                                              const float* __restrict__ inorm_p, const float* __restrict__ onorm_p,
                                              const float* __restrict__ bias, void* __restrict__ outp, float one) {
  constexpr int XPS = 8 / NS;              // XCDs per slice
  constexpr int BPS = (NN + 127) / 128;    // node-groups per slice = 782
  __shared__ int lcsr[LCSR_STORE];
  int bid = blockIdx.x;
  int r = bid & 7;
  int slice = r / XPS;
  int w = (bid >> 3) * XPS + (r % XPS);
  if (w >= BPS) return;
  int t = threadIdx.x;
  int nbase = w * 128;
  int nlim = nbase + 128; if (nlim > NN) nlim = NN;
  int first = rp_p[nbase];
  int last = rp_p[nlim];
  int span = last - first;
  bool useLds = (span <= LCSR_CAP);
  if (useLds) {
    for (int i = t; i < span; i += 256) lcsr[i + (i >> 4)] = csr_p[first + i];
  }
  __syncthreads();
  int pidx = nbase + (t >> 1);
  if (pidx >= NN) return;
  int half = t & 1;
  int beg = rp_p[pidx], end = rp_p[pidx + 1];
  const char* sbp = (const char*)src_arr + ((size_t)slice * NN * 16 + half * 8) * 2;

  float acc[8];
#pragma unroll
  for (int j = 0; j < 8; ++j) acc[j] = 0.f;

  if (useLds) {
    int le = beg - first, lend = end - first;
    for (; le + 3 < lend; le += 4) {
      int i0 = le, i1 = le + 1, i2 = le + 2, i3 = le + 3;
      unsigned o0 = (unsigned)lcsr[i0 + (i0 >> 4)] << 5;
      unsigned o1 = (unsigned)lcsr[i1 + (i1 >> 4)] << 5;
      unsigned o2 = (unsigned)lcsr[i2 + (i2 >> 4)] << 5;
      unsigned o3 = (unsigned)lcsr[i3 + (i3 >> 4)] << 5;
      f16x8 v0 = *(const f16x8*)(sbp + o0);
      f16x8 v1 = *(const f16x8*)(sbp + o1);
      f16x8 v2 = *(const f16x8*)(sbp + o2);
      f16x8 v3 = *(const f16x8*)(sbp + o3);
#pragma unroll
      for (int j = 0; j < 8; ++j) {
        acc[j] = fmaf((float)v3[j], one,
                 fmaf((float)v2[j], one,
                 fmaf((float)v1[j], one,
                 fmaf((float)v0[j], one, acc[j]))));
      }
    }
    for (; le < lend; ++le) {
      f16x8 v0 = *(const f16x8*)(sbp + ((unsigned)lcsr[le + (le >> 4)] << 5));
#pragma unroll
      for (int j = 0; j < 8; ++j) acc[j] = fmaf((float)v0[j], one, acc[j]);
    }
  } else {
    for (int e = beg; e < end; ++e) {
      f16x8 v0 = *(const f16x8*)(sbp + ((size_t)(unsigned)csr_p[e] << 5));
#pragma unroll
      for (int j = 0; j < 8; ++j) acc[j] = fmaf((float)v0[j], one, acc[j]);
    }
  }

  int orig = perm[pidx];
  float inn = inorm_p[pidx];
  int gfb = slice * 16 + half * 8;
  if (MODE == 0) {
    float on = onorm_p[pidx];
    f16x8 o;
#pragma unroll
    for (int j = 0; j < 8; ++j) o[j] = (f16)(fmaxf(acc[j] * inn + bias[gfb + j], 0.f) * on);
    *(f16x8*)((f16*)outp + ((size_t)slice * NN + orig) * 16 + half * 8) = o;
  } else if (MODE == 1) {
    f16x8 o;
#pragma unroll
    for (int j = 0; j < 8; ++j) o[j] = (f16)(acc[j] * inn);
    *(f16x8*)((f16*)outp + ((size_t)slice * NN + orig) * 16 + half * 8) = o;
  } else {
    float* op = (float*)outp + (size_t)orig * (NS * 16) + gfb;
    f32x4 o0, o1;
#pragma unroll
    for (int j = 0; j < 4; ++j) {
      o0[j] = acc[j] * inn + bias[gfb + j];
      o1[j] = acc[4 + j] * inn + bias[gfb + 4 + j];
    }
    *(f32x4*)op = o0;
    *(f32x4*)(op + 4) = o1;
  }
}

extern "C" void kernel_launch(void* const* d_in, const int* in_sizes, int n_in,
                              void* d_out, int out_size, void* d_ws, size_t ws_size,
                              hipStream_t stream) {
  const float* x = (const float*)d_in[0];
  const int* src = (const int*)d_in[1];
  const int* dst = (const int*)d_in[2];
  const float* W1 = (const float*)d_in[3];
  const float* b1 = (const float*)d_in[4];
  const float* W2 = (const float*)d_in[5];
  const float* b2 = (const float*)d_in[6];
  const float* W3 = (const float*)d_in[7];
  const float* b3 = (const float*)d_in[8];

  char* base = (char*)d_ws;
  size_t off = 0;
  auto take = [&](size_t bytes) -> void* {
    void* r = base + off;
    off += (bytes + 255) & ~(size_t)255;
    return r;
  };
  int* outdeg = (int*)take((size_t)NN * 4);
  float* onorm = (float*)take((size_t)NN * 4);
  float* inorm = (float*)take((size_t)NN * 4);
  int* rp = (int*)take((size_t)(NN + 1) * 4);
  int* totals = (int*)take((size_t)P1 * 4);
  int* pbase = (int*)take((size_t)P1 * 4);
  int* hist2d = (int*)take((size_t)NBLK_E * P1 * 4);
  int* base2d = (int*)take((size_t)NBLK_E * P1 * 4);   // reused as dbase2d after k_place
  unsigned* staged = (unsigned*)take((size_t)NE * 4);  // reused as csr_p after k_buildp
  int* csr = (int*)take((size_t)NE * 4);
  // degree-sort buffers
  int* deg = (int*)take((size_t)NN * 4);
  int* perm = (int*)take((size_t)NN * 4);
  int* rp_p = (int*)take((size_t)(NN + 1) * 4);
  float* inorm_p = (float*)take((size_t)NN * 4);
  float* onorm_p = (float*)take((size_t)NN * 4);
  int* dhist2d = (int*)take((size_t)P1 * DBINS * 4);
  int* nbase_g = (int*)take((size_t)DBINS * 4);
  int* ebase_g = (int*)take((size_t)DBINS * 4);
  f16* W1p = (f16*)take((size_t)FIN * FHID * 2);
  f16* W2p = (f16*)take((size_t)FHID * FHID * 2);
  f16* W3p = (f16*)take((size_t)FHID * FCLS * 2);
  f16* B1 = (f16*)take((size_t)NN * FHID * 2);
  f16* B2 = (f16*)take((size_t)NN * FHID * 2);

  int* dbase2d = base2d;          // alias: base2d dead after k_place
  int* csr_p = (int*)staged;      // alias: staged dead after k_buildp

  hipMemsetAsync(outdeg, 0, (size_t)NN * 4, stream);

  k_histA<<<NBLK_E, 256, 0, stream>>>(src, dst, outdeg, hist2d);
  k_pscan<<<1, 256, 0, stream>>>(hist2d, totals, pbase, base2d, rp);
  k_place<<<NBLK_E, 256, 0, stream>>>(src, dst, hist2d, base2d, staged);
  k_buildp<<<P1, 512, 0, stream>>>(staged, totals, pbase, rp, inorm, csr, deg, dhist2d);
  k_onorm<<<(NN + 255) / 256, 256, 0, stream>>>(outdeg, onorm);
  // degree sort: perm + permuted CSR
  k_dscan<<<1, 256, 0, stream>>>(dhist2d, nbase_g, ebase_g, dbase2d, rp_p);
  k_dplace<<<P1, 512, 0, stream>>>(deg, dbase2d, nbase_g, ebase_g, perm, rp_p);
  k_remap<<<(NN + 127) / 128, 256, 0, stream>>>(perm, rp, rp_p, csr, inorm, onorm, csr_p, inorm_p, onorm_p);

  k_packw<FIN, FHID><<<(FIN * FHID + 255) / 256, 256, 0, stream>>>(W1, W1p);
  k_packw<FHID, FHID><<<(FHID * FHID + 255) / 256, 256, 0, stream>>>(W2, W2p);
  k_packw<FHID, FCLS><<<(FHID * FCLS + 255) / 256, 256, 0, stream>>>(W3, W3p);

  const int gemm_grid = (NN + 63) / 64;
  const int bps = (NN + 127) / 128;            // 782
  const int agg8_grid = bps * 8;               // 6256 (XPS=1)
  const int agg4_grid = ((bps + 1) / 2) * 8;   // 3128 (XPS=2)
  // layer 1: t1 = (x*onorm) @ W1  -> sliced B1 (8 slices)
  k_gemm<FIN, FHID, 0><<<gemm_grid, 256, 0, stream>>>(x, W1p, onorm, nullptr, B1);
  // g1 = relu(agg(t1)*inorm + b1) * onorm  -> sliced B2
  k_aggs<8, 0><<<agg8_grid, 256, 0, stream>>>(B1, rp_p, csr_p, perm, inorm_p, onorm_p, b1, B2, 1.0f);
  // agg2 = agg(g1)*inorm  -> sliced B1
  k_aggs<8, 1><<<agg8_grid, 256, 0, stream>>>(B2, rp_p, csr_p, perm, inorm_p, onorm_p, nullptr, B1, 1.0f);
  // g2 = relu(agg2 @ W2 + b2) * onorm  -> sliced B2
  k_gemm<FHID, FHID, 2><<<gemm_grid, 256, 0, stream>>>(B1, W2p, onorm, b2, B2);
  // t3 = g2 @ W3  -> sliced B1 (4 slices used)
  k_gemm<FHID, FCLS, 1><<<gemm_grid, 256, 0, stream>>>(B2, W3p, nullptr, nullptr, B1);
  // out = agg(t3)*inorm + b3  -> dense f32 d_out
  k_aggs<4, 2><<<agg4_grid, 256, 0, stream>>>(B1, rp_p, csr_p, perm, inorm_p, onorm_p, b3, d_out, 1.0f);
}

// Round 10
// 367.683 us; speedup vs baseline: 1.1345x; 1.0976x over previous
//
#include <hip/hip_runtime.h>

#define NN 100000
#define NE 1600000
#define FIN 256
#define FHID 128
#define FCLS 64

// multisplit params: 512 dst-nodes per partition
#define SH1 9
#define P1 196
#define EPB 8192
#define NBLK_E ((NE + EPB - 1) / EPB)

typedef _Float16 f16;
typedef __attribute__((ext_vector_type(8))) _Float16 f16x8;
typedef __attribute__((ext_vector_type(2))) _Float16 f16x2;
typedef __attribute__((ext_vector_type(4))) float f32x4;
typedef __attribute__((ext_vector_type(2))) float f32x2;

// ---------------- pass A: per-block dst-partition histogram + outdeg ----------------
__global__ __launch_bounds__(256) void k_histA(const int* __restrict__ src, const int* __restrict__ dst,
                                               int* __restrict__ outdeg, int* __restrict__ hist2d) {
  __shared__ int lh[P1];
  int t = threadIdx.x;
  for (int i = t; i < P1; i += 256) lh[i] = 0;
  __syncthreads();
  int base = blockIdx.x * EPB;
  int cnt = NE - base; if (cnt > EPB) cnt = EPB;
  for (int i = t; i < cnt; i += 256) {
    atomicAdd(&outdeg[src[base + i]], 1);
    atomicAdd(&lh[dst[base + i] >> SH1], 1);
  }
  __syncthreads();
  for (int i = t; i < P1; i += 256) hist2d[blockIdx.x * P1 + i] = lh[i];
}

// ---------------- pass B: totals, partition bases, per-(block,partition) bases ----------------
__global__ __launch_bounds__(256) void k_pscan(const int* __restrict__ hist2d, int* __restrict__ totals,
                                               int* __restrict__ pbase, int* __restrict__ base2d,
                                               int* __restrict__ rp) {
  __shared__ int sm[256];
  int t = threadIdx.x;
  int tot = 0;
  if (t < P1) {
    for (int b = 0; b < NBLK_E; ++b) tot += hist2d[b * P1 + t];
    totals[t] = tot;
  }
  int v = (t < P1) ? tot : 0;
  int x = v;
  sm[t] = x;
  __syncthreads();
  for (int off = 1; off < 256; off <<= 1) {
    int y = (t >= off) ? sm[t - off] : 0;
    __syncthreads();
    x += y;
    sm[t] = x;
    __syncthreads();
  }
  if (t < P1) {
    int run = x - v;
    pbase[t] = run;
    for (int b = 0; b < NBLK_E; ++b) {
      base2d[b * P1 + t] = run;
      run += hist2d[b * P1 + t];
    }
  }
  if (t == 0) rp[NN] = NE;
}

// ---------------- pass C: per-block LDS counting sort -> contiguous partition runs ----------------
__global__ __launch_bounds__(256) void k_place(const int* __restrict__ src, const int* __restrict__ dst,
                                               const int* __restrict__ hist2d, const int* __restrict__ base2d,
                                               unsigned* __restrict__ staged) {
  __shared__ unsigned buf[EPB];
  __shared__ unsigned char prt[EPB];
  __shared__ int lofs[P1], lcur[P1], lbase[P1];
  __shared__ int sm[256];
  int t = threadIdx.x;
  int b = blockIdx.x;
  int v = 0;
  if (t < P1) {
    v = hist2d[b * P1 + t];
    lbase[t] = base2d[b * P1 + t];
    lcur[t] = 0;
  }
  int x = v;
  sm[t] = x;
  __syncthreads();
  for (int off = 1; off < 256; off <<= 1) {
    int y = (t >= off) ? sm[t - off] : 0;
    __syncthreads();
    x += y;
    sm[t] = x;
    __syncthreads();
  }
  if (t < P1) lofs[t] = x - v;
  __syncthreads();
  int base = b * EPB;
  int cnt = NE - base; if (cnt > EPB) cnt = EPB;
  for (int i = t; i < cnt; i += 256) {
    int s = src[base + i], d = dst[base + i];
    int p = d >> SH1;
    int pos = lofs[p] + atomicAdd(&lcur[p], 1);
    buf[pos] = ((unsigned)s << SH1) | (unsigned)(d & 511);
    prt[pos] = (unsigned char)p;
  }
  __syncthreads();
  for (int i = t; i < cnt; i += 256) {
    int p = prt[i];
    staged[lbase[p] + (i - lofs[p])] = buf[i];
  }
}

// ---------------- pass D: per-partition CSR build ----------------
__global__ __launch_bounds__(512) void k_buildp(const unsigned* __restrict__ staged, const int* __restrict__ totals,
                                                const int* __restrict__ pbase, int* __restrict__ rp,
                                                float* __restrict__ inorm, int* __restrict__ csr) {
  __shared__ int lcnt[512], lofs[512], lcur[512];
  int p = blockIdx.x, t = threadIdx.x;
  int pb = pbase[p], cnt = totals[p];
  lcnt[t] = 0;
  __syncthreads();
  const unsigned* sp = staged + pb;
  for (int i = t; i < cnt; i += 512) atomicAdd(&lcnt[sp[i] & 511], 1);
  __syncthreads();
  int v = lcnt[t];
  int x = v;
  lofs[t] = x;
  __syncthreads();
  for (int off = 1; off < 512; off <<= 1) {
    int y = (t >= off) ? lofs[t - off] : 0;
    __syncthreads();
    x += y;
    lofs[t] = x;
    __syncthreads();
  }
  int excl = x - v;
  lofs[t] = excl;
  lcur[t] = 0;
  int node = (p << SH1) + t;
  if (node < NN) {
    rp[node] = pb + excl;
    int dg = v < 1 ? 1 : v;
    inorm[node] = rsqrtf((float)dg);
  }
  __syncthreads();
  for (int i = t; i < cnt; i += 512) {
    unsigned e = sp[i];
    int d = e & 511;
    int pos = pb + lofs[d] + atomicAdd(&lcur[d], 1);
    csr[pos] = (int)(e >> SH1);
  }
}

__global__ __launch_bounds__(256) void k_onorm(const int* __restrict__ outdeg, float* __restrict__ onorm) {
  int i = blockIdx.x * 256 + threadIdx.x;
  if (i < NN) {
    int od = outdeg[i];
    if (od < 1) od = 1;
    onorm[i] = rsqrtf((float)od);
  }
}

// ---------------- weight pack: fragment-major f16 for mfma 16x16x32 ----------------
template <int K, int NW>
__global__ __launch_bounds__(256) void k_packw(const float* __restrict__ W, f16* __restrict__ Wp) {
  int idx = blockIdx.x * 256 + threadIdx.x;
  if (idx >= K * NW) return;
  constexpr int nT = NW / 16;
  int i = idx & 7;
  int l = (idx >> 3) & 63;
  int rest = idx >> 9;
  int t = rest % nT;
  int s = rest / nT;
  int k = s * 32 + (l >> 4) * 8 + i;
  int n = t * 16 + (l & 15);
  Wp[idx] = (f16)W[k * NW + n];
}

// ---------------- GEMM: [M=NN x K] @ [K x NW] via mfma_f32_16x16x32_f16 ----------------
// I/O feature-sliced in 16-wide slices: T[slice][NN][16] f16 (32 B per node-slice-row).
// MODE 0: A = f32 x (row-major), rows scaled by onorm.   (layer 1)
// MODE 1: A = f16 sliced.                                (layer 3)
// MODE 2: A = f16 sliced; epilogue relu(+bias)*onorm.    (layer 2)
template <int K, int NW, int MODE>
__global__ __launch_bounds__(256) void k_gemm(const void* __restrict__ Asrc, const f16* __restrict__ Wp,
                                              const float* __restrict__ onorm, const float* __restrict__ bias,
                                              f16* __restrict__ Out) {
  constexpr int nS = K / 32, nT = NW / 16;
  int lane = threadIdx.x & 63;
  int w = threadIdx.x >> 6;
  int bm = blockIdx.x * 64 + w * 16;
  int arow = bm + (lane & 15);
  int koff = (lane >> 4) * 8;
  bool rowok = arow < NN;

  f32x4 acc[nT];
#pragma unroll
  for (int t = 0; t < nT; ++t) acc[t] = (f32x4){0.f, 0.f, 0.f, 0.f};

  float ascale = 0.0f;
  if (MODE == 0) ascale = rowok ? onorm[arow] : 0.0f;

  for (int s = 0; s < nS; ++s) {
    f16x8 a = {};
    if (rowok) {
      if (MODE == 0) {
        const float* ap = (const float*)Asrc + (size_t)arow * K + s * 32 + koff;
        f32x4 v0 = *(const f32x4*)ap;
        f32x4 v1 = *(const f32x4*)(ap + 4);
#pragma unroll
        for (int j = 0; j < 4; ++j) {
          a[j] = (f16)(v0[j] * ascale);
          a[4 + j] = (f16)(v1[j] * ascale);
        }
      } else {
        int slice = 2 * s + (koff >> 4);
        a = *(const f16x8*)((const f16*)Asrc + ((size_t)slice * NN + arow) * 16 + (koff & 15));
      }
    }
    const f16* bp = Wp + ((size_t)(s * nT) * 64 + lane) * 8;
#pragma unroll
    for (int t = 0; t < nT; ++t) {
      f16x8 bfr = *(const f16x8*)(bp + t * 512);
      acc[t] = __builtin_amdgcn_mfma_f32_16x16x32_f16(a, bfr, acc[t], 0, 0, 0);
    }
  }

  int crow0 = bm + (lane >> 4) * 4;
  int ccol = lane & 15;
#pragma unroll
  for (int t = 0; t < nT; ++t) {
#pragma unroll
    for (int r = 0; r < 4; ++r) {
      int row = crow0 + r;
      if (row >= NN) continue;
      int col = t * 16 + ccol;
      float v = acc[t][r];
      if (MODE == 2) v = fmaxf(v + bias[col], 0.f) * onorm[row];
      Out[((size_t)t * NN + row) * 16 + ccol] = (f16)v;
    }
  }
}

// ---------------- sliced aggregation: 16B-per-lane gather, LDS-staged indices, 8-deep ----
// Tables [NS][NN][16] f16 (32 B rows). 2 lanes per node per slice, f16x8 loads.
// Block = 128 nodes; its contiguous CSR span staged to LDS once (read-once, coalesced —
// keeps the feature table alone in L2; R8 showed per-lane index reads poison L2).
// blockIdx%8 pins slices to XCDs (NS=8 -> per-XCD gather WS = 3.2 MB, L2-resident).
// Inner loop: 8 indices -> 8 independent f16x8 gathers in flight (MLP ~8 vs R6's ~4).
// MODE 0: out f16 sliced = relu(acc*inorm + bias) * onorm
// MODE 1: out f16 sliced = acc*inorm
// MODE 2: out f32 DENSE [NN][NS*16] = acc*inorm + bias   (final, NS=4 -> 64 cols)
#define LCSR_CAP 2600  // 128 nodes * mean 16 = 2048, sigma 45 -> +12 sigma
template <int NS, int MODE>
__global__ __launch_bounds__(256) void k_aggs(const f16* __restrict__ src_arr, const int* __restrict__ rp,
                                              const int* __restrict__ csr, const float* __restrict__ inorm,
                                              const float* __restrict__ onorm, const float* __restrict__ bias,
                                              void* __restrict__ outp) {
  constexpr int XPS = 8 / NS;              // XCDs per slice
  constexpr int BPS = (NN + 127) / 128;    // node-groups per slice = 782
  __shared__ int lcsr[LCSR_CAP];
  int bid = blockIdx.x;
  int r = bid & 7;
  int slice = r / XPS;
  int w = (bid >> 3) * XPS + (r % XPS);
  if (w >= BPS) return;                    // uniform per block
  int t = threadIdx.x;
  int nbase = w * 128;
  int nlim = nbase + 128; if (nlim > NN) nlim = NN;
  int first = rp[nbase];
  int last = rp[nlim];
  int span = last - first;
  bool useLds = (span <= LCSR_CAP);
  if (useLds) {
    for (int i = t; i < span; i += 256) lcsr[i] = csr[first + i];
  }
  __syncthreads();
  int node = nbase + (t >> 1);
  if (node >= NN) return;
  int half = t & 1;
  int beg = rp[node], end = rp[node + 1];
  const char* sbp = (const char*)src_arr + ((size_t)slice * NN * 16 + half * 8) * 2;

  float acc[8];
#pragma unroll
  for (int j = 0; j < 8; ++j) acc[j] = 0.f;

  if (useLds) {
    int le = beg - first, lend = end - first;
    // 8-deep: 8 LDS index reads, then 8 independent gathers in flight
    for (; le + 7 < lend; le += 8) {
      int x0 = lcsr[le], x1 = lcsr[le + 1], x2 = lcsr[le + 2], x3 = lcsr[le + 3];
      int x4 = lcsr[le + 4], x5 = lcsr[le + 5], x6 = lcsr[le + 6], x7 = lcsr[le + 7];
      f16x8 v0 = *(const f16x8*)(sbp + ((unsigned)x0 << 5));
      f16x8 v1 = *(const f16x8*)(sbp + ((unsigned)x1 << 5));
      f16x8 v2 = *(const f16x8*)(sbp + ((unsigned)x2 << 5));
      f16x8 v3 = *(const f16x8*)(sbp + ((unsigned)x3 << 5));
      f16x8 v4 = *(const f16x8*)(sbp + ((unsigned)x4 << 5));
      f16x8 v5 = *(const f16x8*)(sbp + ((unsigned)x5 << 5));
      f16x8 v6 = *(const f16x8*)(sbp + ((unsigned)x6 << 5));
      f16x8 v7 = *(const f16x8*)(sbp + ((unsigned)x7 << 5));
#pragma unroll
      for (int j = 0; j < 8; ++j) {
        float s01 = (float)v0[j] + (float)v1[j];
        float s23 = (float)v2[j] + (float)v3[j];
        float s45 = (float)v4[j] + (float)v5[j];
        float s67 = (float)v6[j] + (float)v7[j];
        acc[j] += (s01 + s23) + (s45 + s67);
      }
    }
    for (; le + 3 < lend; le += 4) {
      int x0 = lcsr[le], x1 = lcsr[le + 1], x2 = lcsr[le + 2], x3 = lcsr[le + 3];
      f16x8 v0 = *(const f16x8*)(sbp + ((unsigned)x0 << 5));
      f16x8 v1 = *(const f16x8*)(sbp + ((unsigned)x1 << 5));
      f16x8 v2 = *(const f16x8*)(sbp + ((unsigned)x2 << 5));
      f16x8 v3 = *(const f16x8*)(sbp + ((unsigned)x3 << 5));
#pragma unroll
      for (int j = 0; j < 8; ++j)
        acc[j] += ((float)v0[j] + (float)v1[j]) + ((float)v2[j] + (float)v3[j]);
    }
    for (; le < lend; ++le) {
      f16x8 v0 = *(const f16x8*)(sbp + ((unsigned)lcsr[le] << 5));
#pragma unroll
      for (int j = 0; j < 8; ++j) acc[j] += (float)v0[j];
    }
  } else {
    for (int e = beg; e < end; ++e) {
      f16x8 v0 = *(const f16x8*)(sbp + ((size_t)(unsigned)csr[e] << 5));
#pragma unroll
      for (int j = 0; j < 8; ++j) acc[j] += (float)v0[j];
    }
  }

  float inn = inorm[node];
  int gfb = slice * 16 + half * 8;
  if (MODE == 0) {
    float on = onorm[node];
    f16x8 o;
#pragma unroll
    for (int j = 0; j < 8; ++j) o[j] = (f16)(fmaxf(acc[j] * inn + bias[gfb + j], 0.f) * on);
    *(f16x8*)((f16*)outp + ((size_t)slice * NN + node) * 16 + half * 8) = o;
  } else if (MODE == 1) {
    f16x8 o;
#pragma unroll
    for (int j = 0; j < 8; ++j) o[j] = (f16)(acc[j] * inn);
    *(f16x8*)((f16*)outp + ((size_t)slice * NN + node) * 16 + half * 8) = o;
  } else {
    float* op = (float*)outp + (size_t)node * (NS * 16) + gfb;
    f32x4 o0, o1;
#pragma unroll
    for (int j = 0; j < 4; ++j) {
      o0[j] = acc[j] * inn + bias[gfb + j];
      o1[j] = acc[4 + j] * inn + bias[gfb + 4 + j];
    }
    *(f32x4*)op = o0;
    *(f32x4*)(op + 4) = o1;
  }
}

extern "C" void kernel_launch(void* const* d_in, const int* in_sizes, int n_in,
                              void* d_out, int out_size, void* d_ws, size_t ws_size,
                              hipStream_t stream) {
  const float* x = (const float*)d_in[0];
  const int* src = (const int*)d_in[1];
  const int* dst = (const int*)d_in[2];
  const float* W1 = (const float*)d_in[3];
  const float* b1 = (const float*)d_in[4];
  const float* W2 = (const float*)d_in[5];
  const float* b2 = (const float*)d_in[6];
  const float* W3 = (const float*)d_in[7];
  const float* b3 = (const float*)d_in[8];

  char* base = (char*)d_ws;
  size_t off = 0;
  auto take = [&](size_t bytes) -> void* {
    void* r = base + off;
    off += (bytes + 255) & ~(size_t)255;
    return r;
  };
  int* outdeg = (int*)take((size_t)NN * 4);
  float* onorm = (float*)take((size_t)NN * 4);
  float* inorm = (float*)take((size_t)NN * 4);
  int* rp = (int*)take((size_t)(NN + 1) * 4);
  int* totals = (int*)take((size_t)P1 * 4);
  int* pbase = (int*)take((size_t)P1 * 4);
  int* hist2d = (int*)take((size_t)NBLK_E * P1 * 4);
  int* base2d = (int*)take((size_t)NBLK_E * P1 * 4);
  unsigned* staged = (unsigned*)take((size_t)NE * 4);
  int* csr = (int*)take((size_t)NE * 4);
  f16* W1p = (f16*)take((size_t)FIN * FHID * 2);
  f16* W2p = (f16*)take((size_t)FHID * FHID * 2);
  f16* W3p = (f16*)take((size_t)FHID * FCLS * 2);
  f16* B1 = (f16*)take((size_t)NN * FHID * 2);
  f16* B2 = (f16*)take((size_t)NN * FHID * 2);

  hipMemsetAsync(outdeg, 0, (size_t)NN * 4, stream);

  k_histA<<<NBLK_E, 256, 0, stream>>>(src, dst, outdeg, hist2d);
  k_pscan<<<1, 256, 0, stream>>>(hist2d, totals, pbase, base2d, rp);
  k_place<<<NBLK_E, 256, 0, stream>>>(src, dst, hist2d, base2d, staged);
  k_buildp<<<P1, 512, 0, stream>>>(staged, totals, pbase, rp, inorm, csr);
  k_onorm<<<(NN + 255) / 256, 256, 0, stream>>>(outdeg, onorm);

  k_packw<FIN, FHID><<<(FIN * FHID + 255) / 256, 256, 0, stream>>>(W1, W1p);
  k_packw<FHID, FHID><<<(FHID * FHID + 255) / 256, 256, 0, stream>>>(W2, W2p);
  k_packw<FHID, FCLS><<<(FHID * FCLS + 255) / 256, 256, 0, stream>>>(W3, W3p);

  const int gemm_grid = (NN + 63) / 64;
  const int bps = (NN + 127) / 128;            // 782
  const int agg8_grid = bps * 8;               // 6256 (XPS=1)
  const int agg4_grid = ((bps + 1) / 2) * 8;   // 3128 (XPS=2)
  // layer 1: t1 = (x*onorm) @ W1  -> sliced B1 (8 slices)
  k_gemm<FIN, FHID, 0><<<gemm_grid, 256, 0, stream>>>(x, W1p, onorm, nullptr, B1);
  // g1 = relu(agg(t1)*inorm + b1) * onorm  -> sliced B2
  k_aggs<8, 0><<<agg8_grid, 256, 0, stream>>>(B1, rp, csr, inorm, onorm, b1, B2);
  // agg2 = agg(g1)*inorm  -> sliced B1
  k_aggs<8, 1><<<agg8_grid, 256, 0, stream>>>(B2, rp, csr, inorm, nullptr, nullptr, B1);
  // g2 = relu(agg2 @ W2 + b2) * onorm  -> sliced B2
  k_gemm<FHID, FHID, 2><<<gemm_grid, 256, 0, stream>>>(B1, W2p, onorm, b2, B2);
  // t3 = g2 @ W3  -> sliced B1 (4 slices used)
  k_gemm<FHID, FCLS, 1><<<gemm_grid, 256, 0, stream>>>(B2, W3p, nullptr, nullptr, B1);
  // out = agg(t3)*inorm + b3  -> dense f32 d_out
  k_aggs<4, 2><<<agg4_grid, 256, 0, stream>>>(B1, rp, csr, inorm, nullptr, b3, d_out);
}

// Round 11
// 346.273 us; speedup vs baseline: 1.2047x; 1.0618x over previous
//
#include <hip/hip_runtime.h>

#define NN 100000
#define NE 1600000
#define FIN 256
#define FHID 128
#define FCLS 64

// multisplit params: 512 dst-nodes per partition
#define SH1 9
#define P1 196
#define EPB 8192
#define NBLK_E ((NE + EPB - 1) / EPB)

typedef _Float16 f16;
typedef __attribute__((ext_vector_type(8))) _Float16 f16x8;
typedef __attribute__((ext_vector_type(2))) _Float16 f16x2;
typedef __attribute__((ext_vector_type(4))) float f32x4;
typedef __attribute__((ext_vector_type(2))) float f32x2;

// ---------------- pass A: per-block dst-partition histogram + outdeg ----------------
__global__ __launch_bounds__(256) void k_histA(const int* __restrict__ src, const int* __restrict__ dst,
                                               int* __restrict__ outdeg, int* __restrict__ hist2d) {
  __shared__ int lh[P1];
  int t = threadIdx.x;
  for (int i = t; i < P1; i += 256) lh[i] = 0;
  __syncthreads();
  int base = blockIdx.x * EPB;
  int cnt = NE - base; if (cnt > EPB) cnt = EPB;
  for (int i = t; i < cnt; i += 256) {
    atomicAdd(&outdeg[src[base + i]], 1);
    atomicAdd(&lh[dst[base + i] >> SH1], 1);
  }
  __syncthreads();
  for (int i = t; i < P1; i += 256) hist2d[blockIdx.x * P1 + i] = lh[i];
}

// ---------------- pass B: totals, partition bases, per-(block,partition) bases ----------------
__global__ __launch_bounds__(256) void k_pscan(const int* __restrict__ hist2d, int* __restrict__ totals,
                                               int* __restrict__ pbase, int* __restrict__ base2d,
                                               int* __restrict__ rp) {
  __shared__ int sm[256];
  int t = threadIdx.x;
  int tot = 0;
  if (t < P1) {
    for (int b = 0; b < NBLK_E; ++b) tot += hist2d[b * P1 + t];
    totals[t] = tot;
  }
  int v = (t < P1) ? tot : 0;
  int x = v;
  sm[t] = x;
  __syncthreads();
  for (int off = 1; off < 256; off <<= 1) {
    int y = (t >= off) ? sm[t - off] : 0;
    __syncthreads();
    x += y;
    sm[t] = x;
    __syncthreads();
  }
  if (t < P1) {
    int run = x - v;
    pbase[t] = run;
    for (int b = 0; b < NBLK_E; ++b) {
      base2d[b * P1 + t] = run;
      run += hist2d[b * P1 + t];
    }
  }
  if (t == 0) rp[NN] = NE;
}

// ---------------- pass C: per-block LDS counting sort -> contiguous partition runs ----------------
__global__ __launch_bounds__(256) void k_place(const int* __restrict__ src, const int* __restrict__ dst,
                                               const int* __restrict__ hist2d, const int* __restrict__ base2d,
                                               unsigned* __restrict__ staged) {
  __shared__ unsigned buf[EPB];
  __shared__ unsigned char prt[EPB];
  __shared__ int lofs[P1], lcur[P1], lbase[P1];
  __shared__ int sm[256];
  int t = threadIdx.x;
  int b = blockIdx.x;
  int v = 0;
  if (t < P1) {
    v = hist2d[b * P1 + t];
    lbase[t] = base2d[b * P1 + t];
    lcur[t] = 0;
  }
  int x = v;
  sm[t] = x;
  __syncthreads();
  for (int off = 1; off < 256; off <<= 1) {
    int y = (t >= off) ? sm[t - off] : 0;
    __syncthreads();
    x += y;
    sm[t] = x;
    __syncthreads();
  }
  if (t < P1) lofs[t] = x - v;
  __syncthreads();
  int base = b * EPB;
  int cnt = NE - base; if (cnt > EPB) cnt = EPB;
  for (int i = t; i < cnt; i += 256) {
    int s = src[base + i], d = dst[base + i];
    int p = d >> SH1;
    int pos = lofs[p] + atomicAdd(&lcur[p], 1);
    buf[pos] = ((unsigned)s << SH1) | (unsigned)(d & 511);
    prt[pos] = (unsigned char)p;
  }
  __syncthreads();
  for (int i = t; i < cnt; i += 256) {
    int p = prt[i];
    staged[lbase[p] + (i - lofs[p])] = buf[i];
  }
}

// ---------------- pass D: per-partition CSR build (+ inorm + onorm) ----------------
__global__ __launch_bounds__(512) void k_buildp(const unsigned* __restrict__ staged, const int* __restrict__ totals,
                                                const int* __restrict__ pbase, const int* __restrict__ outdeg,
                                                int* __restrict__ rp, float* __restrict__ inorm,
                                                float* __restrict__ onorm, int* __restrict__ csr) {
  __shared__ int lcnt[512], lofs[512], lcur[512];
  int p = blockIdx.x, t = threadIdx.x;
  int pb = pbase[p], cnt = totals[p];
  lcnt[t] = 0;
  __syncthreads();
  const unsigned* sp = staged + pb;
  for (int i = t; i < cnt; i += 512) atomicAdd(&lcnt[sp[i] & 511], 1);
  __syncthreads();
  int v = lcnt[t];
  int x = v;
  lofs[t] = x;
  __syncthreads();
  for (int off = 1; off < 512; off <<= 1) {
    int y = (t >= off) ? lofs[t - off] : 0;
    __syncthreads();
    x += y;
    lofs[t] = x;
    __syncthreads();
  }
  int excl = x - v;
  lofs[t] = excl;
  lcur[t] = 0;
  int node = (p << SH1) + t;
  if (node < NN) {
    rp[node] = pb + excl;
    int dg = v < 1 ? 1 : v;
    inorm[node] = rsqrtf((float)dg);
    int od = outdeg[node];
    if (od < 1) od = 1;
    onorm[node] = rsqrtf((float)od);
  }
  __syncthreads();
  for (int i = t; i < cnt; i += 512) {
    unsigned e = sp[i];
    int d = e & 511;
    int pos = pb + lofs[d] + atomicAdd(&lcur[d], 1);
    csr[pos] = (int)(e >> SH1);
  }
}

// ---------------- weight pack: fragment-major f16 for mfma 16x16x32 ----------------
template <int K, int NW>
__global__ __launch_bounds__(256) void k_packw(const float* __restrict__ W, f16* __restrict__ Wp) {
  int idx = blockIdx.x * 256 + threadIdx.x;
  if (idx >= K * NW) return;
  constexpr int nT = NW / 16;
  int i = idx & 7;
  int l = (idx >> 3) & 63;
  int rest = idx >> 9;
  int t = rest % nT;
  int s = rest / nT;
  int k = s * 32 + (l >> 4) * 8 + i;
  int n = t * 16 + (l & 15);
  Wp[idx] = (f16)W[k * NW + n];
}

// ---------------- GEMM: [M=NN x K] @ [K x NW] via mfma_f32_16x16x32_f16 ----------------
// I/O feature-sliced in 32-wide slices: T[slice][NN][32] f16 (64 B per node-slice-row).
// k-subtile s == slice s for A; output col>>5 == slice.
// MODE 0: A = f32 x (row-major), rows scaled by onorm.   (layer 1)
// MODE 1: A = f16 sliced-32.                             (layer 3)
// MODE 2: A = f16 sliced-32; epilogue relu(+bias)*onorm. (layer 2)
template <int K, int NW, int MODE>
__global__ __launch_bounds__(256) void k_gemm(const void* __restrict__ Asrc, const f16* __restrict__ Wp,
                                              const float* __restrict__ onorm, const float* __restrict__ bias,
                                              f16* __restrict__ Out) {
  constexpr int nS = K / 32, nT = NW / 16;
  int lane = threadIdx.x & 63;
  int w = threadIdx.x >> 6;
  int bm = blockIdx.x * 64 + w * 16;
  int arow = bm + (lane & 15);
  int koff = (lane >> 4) * 8;
  bool rowok = arow < NN;

  f32x4 acc[nT];
#pragma unroll
  for (int t = 0; t < nT; ++t) acc[t] = (f32x4){0.f, 0.f, 0.f, 0.f};

  float ascale = 0.0f;
  if (MODE == 0) ascale = rowok ? onorm[arow] : 0.0f;

  for (int s = 0; s < nS; ++s) {
    f16x8 a = {};
    if (rowok) {
      if (MODE == 0) {
        const float* ap = (const float*)Asrc + (size_t)arow * K + s * 32 + koff;
        f32x4 v0 = *(const f32x4*)ap;
        f32x4 v1 = *(const f32x4*)(ap + 4);
#pragma unroll
        for (int j = 0; j < 4; ++j) {
          a[j] = (f16)(v0[j] * ascale);
          a[4 + j] = (f16)(v1[j] * ascale);
        }
      } else {
        // sliced-32 A: k-subtile s IS slice s
        a = *(const f16x8*)((const f16*)Asrc + ((size_t)s * NN + arow) * 32 + koff);
      }
    }
    const f16* bp = Wp + ((size_t)(s * nT) * 64 + lane) * 8;
#pragma unroll
    for (int t = 0; t < nT; ++t) {
      f16x8 bfr = *(const f16x8*)(bp + t * 512);
      acc[t] = __builtin_amdgcn_mfma_f32_16x16x32_f16(a, bfr, acc[t], 0, 0, 0);
    }
  }

  int crow0 = bm + (lane >> 4) * 4;
  int ccol = lane & 15;
#pragma unroll
  for (int t = 0; t < nT; ++t) {
#pragma unroll
    for (int r = 0; r < 4; ++r) {
      int row = crow0 + r;
      if (row >= NN) continue;
      int col = t * 16 + ccol;
      float v = acc[t][r];
      if (MODE == 2) v = fmaxf(v + bias[col], 0.f) * onorm[row];
      Out[((size_t)(col >> 5) * NN + row) * 32 + (col & 31)] = (f16)v;
    }
  }
}

// ---------------- sliced aggregation: 64B rows, 4 lanes/node, LDS-staged indices ----------
// Tables [NS][NN][32] f16 (64 B per node-slice-row = one FULL cache line, fully consumed).
// Requests per edge per dispatch = NS (4 for 128-wide layers, 2 for final) vs 8 before.
// Block = 64 nodes; contiguous CSR span staged to LDS once (read-once, coalesced).
// blockIdx%8 maps slices to XCDs (NS=4: 2 XCDs/slice -> per-XCD WS 6.4 MB, ~55% L2 + L3).
// MODE 0: out f16 sliced-32 = relu(acc*inorm + bias) * onorm
// MODE 1: out f16 sliced-32 = acc*inorm
// MODE 2: out f32 DENSE [NN][NS*32] = acc*inorm + bias   (final, NS=2 -> 64 cols)
#define LCSR_CAP 1408  // 64 nodes * mean 16 = 1024, sigma 32 -> +12 sigma
template <int NS, int MODE>
__global__ __launch_bounds__(256) void k_aggs(const f16* __restrict__ src_arr, const int* __restrict__ rp,
                                              const int* __restrict__ csr, const float* __restrict__ inorm,
                                              const float* __restrict__ onorm, const float* __restrict__ bias,
                                              void* __restrict__ outp) {
  constexpr int XPS = 8 / NS;              // XCDs per slice
  constexpr int BPS = (NN + 63) / 64;      // node-groups per slice = 1563
  __shared__ int lcsr[LCSR_CAP];
  int bid = blockIdx.x;
  int r = bid & 7;
  int slice = r / XPS;
  int w = (bid >> 3) * XPS + (r % XPS);
  if (w >= BPS) return;                    // uniform per block
  int t = threadIdx.x;
  int nbase = w * 64;
  int nlim = nbase + 64; if (nlim > NN) nlim = NN;
  int first = rp[nbase];
  int last = rp[nlim];
  int span = last - first;
  bool useLds = (span <= LCSR_CAP);
  if (useLds) {
    for (int i = t; i < span; i += 256) lcsr[i] = csr[first + i];
  }
  __syncthreads();
  int node = nbase + (t >> 2);
  if (node >= NN) return;
  int q = t & 3;                           // quarter of the 64B row
  int beg = rp[node], end = rp[node + 1];
  const char* sbp = (const char*)src_arr + ((size_t)slice * NN * 32 + q * 8) * 2;

  float acc[8];
#pragma unroll
  for (int j = 0; j < 8; ++j) acc[j] = 0.f;

  if (useLds) {
    int le = beg - first, lend = end - first;
    for (; le + 7 < lend; le += 8) {
      int x0 = lcsr[le], x1 = lcsr[le + 1], x2 = lcsr[le + 2], x3 = lcsr[le + 3];
      int x4 = lcsr[le + 4], x5 = lcsr[le + 5], x6 = lcsr[le + 6], x7 = lcsr[le + 7];
      f16x8 v0 = *(const f16x8*)(sbp + ((size_t)(unsigned)x0 << 6));
      f16x8 v1 = *(const f16x8*)(sbp + ((size_t)(unsigned)x1 << 6));
      f16x8 v2 = *(const f16x8*)(sbp + ((size_t)(unsigned)x2 << 6));
      f16x8 v3 = *(const f16x8*)(sbp + ((size_t)(unsigned)x3 << 6));
      f16x8 v4 = *(const f16x8*)(sbp + ((size_t)(unsigned)x4 << 6));
      f16x8 v5 = *(const f16x8*)(sbp + ((size_t)(unsigned)x5 << 6));
      f16x8 v6 = *(const f16x8*)(sbp + ((size_t)(unsigned)x6 << 6));
      f16x8 v7 = *(const f16x8*)(sbp + ((size_t)(unsigned)x7 << 6));
#pragma unroll
      for (int j = 0; j < 8; ++j) {
        float s01 = (float)v0[j] + (float)v1[j];
        float s23 = (float)v2[j] + (float)v3[j];
        float s45 = (float)v4[j] + (float)v5[j];
        float s67 = (float)v6[j] + (float)v7[j];
        acc[j] += (s01 + s23) + (s45 + s67);
      }
    }
    for (; le + 3 < lend; le += 4) {
      int x0 = lcsr[le], x1 = lcsr[le + 1], x2 = lcsr[le + 2], x3 = lcsr[le + 3];
      f16x8 v0 = *(const f16x8*)(sbp + ((size_t)(unsigned)x0 << 6));
      f16x8 v1 = *(const f16x8*)(sbp + ((size_t)(unsigned)x1 << 6));
      f16x8 v2 = *(const f16x8*)(sbp + ((size_t)(unsigned)x2 << 6));
      f16x8 v3 = *(const f16x8*)(sbp + ((size_t)(unsigned)x3 << 6));
#pragma unroll
      for (int j = 0; j < 8; ++j)
        acc[j] += ((float)v0[j] + (float)v1[j]) + ((float)v2[j] + (float)v3[j]);
    }
    for (; le < lend; ++le) {
      f16x8 v0 = *(const f16x8*)(sbp + ((size_t)(unsigned)lcsr[le] << 6));
#pragma unroll
      for (int j = 0; j < 8; ++j) acc[j] += (float)v0[j];
    }
  } else {
    for (int e = beg; e < end; ++e) {
      f16x8 v0 = *(const f16x8*)(sbp + ((size_t)(unsigned)csr[e] << 6));
#pragma unroll
      for (int j = 0; j < 8; ++j) acc[j] += (float)v0[j];
    }
  }

  float inn = inorm[node];
  int gfb = slice * 32 + q * 8;            // global feature col base
  if (MODE == 0) {
    float on = onorm[node];
    f16x8 o;
#pragma unroll
    for (int j = 0; j < 8; ++j) o[j] = (f16)(fmaxf(acc[j] * inn + bias[gfb + j], 0.f) * on);
    *(f16x8*)((f16*)outp + ((size_t)slice * NN + node) * 32 + q * 8) = o;
  } else if (MODE == 1) {
    f16x8 o;
#pragma unroll
    for (int j = 0; j < 8; ++j) o[j] = (f16)(acc[j] * inn);
    *(f16x8*)((f16*)outp + ((size_t)slice * NN + node) * 32 + q * 8) = o;
  } else {
    float* op = (float*)outp + (size_t)node * (NS * 32) + gfb;
    f32x4 o0, o1;
#pragma unroll
    for (int j = 0; j < 4; ++j) {
      o0[j] = acc[j] * inn + bias[gfb + j];
      o1[j] = acc[4 + j] * inn + bias[gfb + 4 + j];
    }
    *(f32x4*)op = o0;
    *(f32x4*)(op + 4) = o1;
  }
}

extern "C" void kernel_launch(void* const* d_in, const int* in_sizes, int n_in,
                              void* d_out, int out_size, void* d_ws, size_t ws_size,
                              hipStream_t stream) {
  const float* x = (const float*)d_in[0];
  const int* src = (const int*)d_in[1];
  const int* dst = (const int*)d_in[2];
  const float* W1 = (const float*)d_in[3];
  const float* b1 = (const float*)d_in[4];
  const float* W2 = (const float*)d_in[5];
  const float* b2 = (const float*)d_in[6];
  const float* W3 = (const float*)d_in[7];
  const float* b3 = (const float*)d_in[8];

  char* base = (char*)d_ws;
  size_t off = 0;
  auto take = [&](size_t bytes) -> void* {
    void* r = base + off;
    off += (bytes + 255) & ~(size_t)255;
    return r;
  };
  int* outdeg = (int*)take((size_t)NN * 4);
  float* onorm = (float*)take((size_t)NN * 4);
  float* inorm = (float*)take((size_t)NN * 4);
  int* rp = (int*)take((size_t)(NN + 1) * 4);
  int* totals = (int*)take((size_t)P1 * 4);
  int* pbase = (int*)take((size_t)P1 * 4);
  int* hist2d = (int*)take((size_t)NBLK_E * P1 * 4);
  int* base2d = (int*)take((size_t)NBLK_E * P1 * 4);
  unsigned* staged = (unsigned*)take((size_t)NE * 4);
  int* csr = (int*)take((size_t)NE * 4);
  f16* W1p = (f16*)take((size_t)FIN * FHID * 2);
  f16* W2p = (f16*)take((size_t)FHID * FHID * 2);
  f16* W3p = (f16*)take((size_t)FHID * FCLS * 2);
  f16* B1 = (f16*)take((size_t)NN * FHID * 2);
  f16* B2 = (f16*)take((size_t)NN * FHID * 2);

  hipMemsetAsync(outdeg, 0, (size_t)NN * 4, stream);

  k_histA<<<NBLK_E, 256, 0, stream>>>(src, dst, outdeg, hist2d);
  k_pscan<<<1, 256, 0, stream>>>(hist2d, totals, pbase, base2d, rp);
  k_place<<<NBLK_E, 256, 0, stream>>>(src, dst, hist2d, base2d, staged);
  k_buildp<<<P1, 512, 0, stream>>>(staged, totals, pbase, outdeg, rp, inorm, onorm, csr);

  k_packw<FIN, FHID><<<(FIN * FHID + 255) / 256, 256, 0, stream>>>(W1, W1p);
  k_packw<FHID, FHID><<<(FHID * FHID + 255) / 256, 256, 0, stream>>>(W2, W2p);
  k_packw<FHID, FCLS><<<(FHID * FCLS + 255) / 256, 256, 0, stream>>>(W3, W3p);

  const int gemm_grid = (NN + 63) / 64;
  const int bps = (NN + 63) / 64;              // 1563
  const int agg4_grid = ((bps + 1) / 2) * 8;   // 6256 (NS=4, XPS=2)
  const int agg2_grid = ((bps + 3) / 4) * 8;   // 3128 (NS=2, XPS=4)
  // layer 1: t1 = (x*onorm) @ W1  -> sliced-32 B1 (4 slices)
  k_gemm<FIN, FHID, 0><<<gemm_grid, 256, 0, stream>>>(x, W1p, onorm, nullptr, B1);
  // g1 = relu(agg(t1)*inorm + b1) * onorm  -> sliced-32 B2
  k_aggs<4, 0><<<agg4_grid, 256, 0, stream>>>(B1, rp, csr, inorm, onorm, b1, B2);
  // agg2 = agg(g1)*inorm  -> sliced-32 B1
  k_aggs<4, 1><<<agg4_grid, 256, 0, stream>>>(B2, rp, csr, inorm, nullptr, nullptr, B1);
  // g2 = relu(agg2 @ W2 + b2) * onorm  -> sliced-32 B2
  k_gemm<FHID, FHID, 2><<<gemm_grid, 256, 0, stream>>>(B1, W2p, onorm, b2, B2);
  // t3 = g2 @ W3  -> sliced-32 B1 (2 slices used)
  k_gemm<FHID, FCLS, 1><<<gemm_grid, 256, 0, stream>>>(B2, W3p, nullptr, nullptr, B1);
  // out = agg(t3)*inorm + b3  -> dense f32 d_out
  k_aggs<2, 2><<<agg2_grid, 256, 0, stream>>>(B1, rp, csr, inorm, nullptr, b3, d_out);
}